// Round 2
// baseline (16854.361 us; speedup 1.0000x reference)
//
#include <hip/hip_runtime.h>
#include <hip/hip_bf16.h>
#include <hip/hip_cooperative_groups.h>

namespace cg = cooperative_groups;

// RNNLayer: B=64, T=512, D_IN=D_H=D_OUT=1024.
// h' = [x,h]@W_h^T + b_h ; o = [x,h]@W_o^T + b_o
// Phase 1: parallel input-projection GEMM (Xh packed f16, Out f32 initial).
// Phase 2: ONE persistent cooperative kernel, weights register-resident,
//          one grid.sync() per step.

typedef _Float16 f16;
typedef _Float16 f16x8 __attribute__((ext_vector_type(8)));
typedef _Float16 f16x4 __attribute__((ext_vector_type(4)));
typedef float f32x4 __attribute__((ext_vector_type(4)));

#define T_LEN 512
#define BATCH 64
#define M_TOT (BATCH * T_LEN)   // 32768

// ---------- prep: stacked fp16 weights ----------
// Wx[n][k] = W(n)[k] (input half); Wr[n][k] = W(n)[1024+k] (recurrent half)
// rows n<1024 -> W_h row n ; n>=1024 -> W_o row n-1024
__global__ void k_prep_w(const float* __restrict__ Wh, const float* __restrict__ Wo,
                         f16* __restrict__ Wx, f16* __restrict__ Wr) {
    int n = blockIdx.x;              // 0..2047
    int t4 = threadIdx.x * 4;        // 0..1020
    const float* src = (n < 1024) ? (Wh + (size_t)n * 2048)
                                  : (Wo + (size_t)(n - 1024) * 2048);
    float4 a = *reinterpret_cast<const float4*>(src + t4);
    float4 b = *reinterpret_cast<const float4*>(src + 1024 + t4);
    f16x4 va, vb;
    va[0]=(f16)a.x; va[1]=(f16)a.y; va[2]=(f16)a.z; va[3]=(f16)a.w;
    vb[0]=(f16)b.x; vb[1]=(f16)b.y; vb[2]=(f16)b.z; vb[3]=(f16)b.w;
    *reinterpret_cast<f16x4*>(Wx + (size_t)n*1024 + t4) = va;
    *reinterpret_cast<f16x4*>(Wr + (size_t)n*1024 + t4) = vb;
}

// ---------- initial hidden f32 -> packed f16 [kblk 128][b 64][8] ----------
__global__ void k_init_h(const float* __restrict__ H0, f16* __restrict__ hP) {
    int tid = blockIdx.x * 256 + threadIdx.x;   // 8192
    int b = tid >> 7, kb = tid & 127;
    float4 x0 = *reinterpret_cast<const float4*>(H0 + (size_t)b*1024 + kb*8);
    float4 x1 = *reinterpret_cast<const float4*>(H0 + (size_t)b*1024 + kb*8 + 4);
    f16x8 v;
    v[0]=(f16)x0.x; v[1]=(f16)x0.y; v[2]=(f16)x0.z; v[3]=(f16)x0.w;
    v[4]=(f16)x1.x; v[5]=(f16)x1.y; v[6]=(f16)x1.z; v[7]=(f16)x1.w;
    *reinterpret_cast<f16x8*>(hP + ((size_t)kb*64 + b)*8) = v;
}

// ---------- phase 1: input projection GEMM ----------
// A = X f32 [32768][1024] (rows m = b*512+t), B = Wx f16 [2048][1024]
// n<1024:  Xh packed [t][cblk 128][b 64][8] f16 = dot + b_h
// n>=1024: Out[b][t][n-1024] f32 = dot + b_o
__global__ __launch_bounds__(256) void k_gemm1(
    const float* __restrict__ Af, const f16* __restrict__ Bm,
    const float* __restrict__ bh, const float* __restrict__ bo,
    f16* __restrict__ Xh, float* __restrict__ Out)
{
    __shared__ f16 As[128][40];
    __shared__ f16 Bs[128][40];
    int m0 = blockIdx.x * 128;
    int n0 = blockIdx.y * 128;
    int t = threadIdx.x;
    int l = t & 63, wid = t >> 6;
    int wm = wid >> 1, wn = wid & 1;
    int lm = l & 15, lh = l >> 4;

    f32x4 acc[4][4];
    #pragma unroll
    for (int i = 0; i < 4; i++)
        #pragma unroll
        for (int j = 0; j < 4; j++) acc[i][j] = (f32x4){0.f,0.f,0.f,0.f};

    for (int kt = 0; kt < 32; ++kt) {
        int k0 = kt * 32;
        __syncthreads();
        #pragma unroll
        for (int c = t; c < 1024; c += 256) {
            int row = c >> 3, q = c & 7;
            float4 a = *reinterpret_cast<const float4*>(Af + (size_t)(m0+row)*1024 + k0 + q*4);
            f16x4 v; v[0]=(f16)a.x; v[1]=(f16)a.y; v[2]=(f16)a.z; v[3]=(f16)a.w;
            *reinterpret_cast<f16x4*>(&As[row][q*4]) = v;
        }
        #pragma unroll
        for (int c = t; c < 512; c += 256) {
            int row = c >> 2, q = c & 3;
            *reinterpret_cast<float4*>(&Bs[row][q*8]) =
                *reinterpret_cast<const float4*>(Bm + (size_t)(n0+row)*1024 + k0 + q*8);
        }
        __syncthreads();

        f16x8 af[4], bf[4];
        #pragma unroll
        for (int i = 0; i < 4; i++)
            af[i] = *reinterpret_cast<const f16x8*>(&As[64*wm + 16*i + lm][8*lh]);
        #pragma unroll
        for (int j = 0; j < 4; j++)
            bf[j] = *reinterpret_cast<const f16x8*>(&Bs[64*wn + 16*j + lm][8*lh]);
        #pragma unroll
        for (int i = 0; i < 4; i++)
            #pragma unroll
            for (int j = 0; j < 4; j++)
                acc[i][j] = __builtin_amdgcn_mfma_f32_16x16x32_f16(af[i], bf[j], acc[i][j], 0, 0, 0);
    }

    int r0 = lh * 4;
    bool isH = (n0 < 1024);
    #pragma unroll
    for (int i = 0; i < 4; i++)
        #pragma unroll
        for (int j = 0; j < 4; j++) {
            int gmb = m0 + 64*wm + 16*i + r0;
            int gn  = n0 + 64*wn + 16*j + lm;
            #pragma unroll
            for (int r = 0; r < 4; r++) {
                float v = acc[i][j][r];
                int gm = gmb + r;
                if (isH) {
                    int tt = gm & 511, bb = gm >> 9;
                    Xh[((size_t)tt*8192 + (size_t)(gn>>3)*64 + bb)*8 + (gn&7)] = (f16)(v + bh[gn]);
                } else {
                    Out[(size_t)gm*1024 + (gn - 1024)] = v + bo[gn - 1024];
                }
            }
        }
}

// ---------- phase 2: persistent recurrent kernel ----------
// grid = 128 WGs x 256 thr. WG wg: mb = wg&3 (16 batch rows), nc = wg>>2 (64 cols).
// wave w owns cols nc*64 + w*16 .. +16, full K=1024, Wr slice in 128 VGPRs.
// h packed [2][kblk 128][b 64][8] f16 ping-pong.
__global__ __launch_bounds__(256, 1) void k_rnn(
    const f16* __restrict__ Wr,    // [2048][1024]
    const f16* __restrict__ Xh,    // [512][128][64][8] packed (x@Wh^T + b_h)
    f16* __restrict__ hP,          // [2][128][64][8]
    float* __restrict__ Out)       // [64][512][1024], pre-filled with x@Wo^T + b_o
{
    cg::grid_group grid = cg::this_grid();
    int wg = blockIdx.x;
    int mb = wg & 3;
    int nc = wg >> 2;                 // 0..31 ; <16 -> h-half
    int w  = threadIdx.x >> 6;
    int l  = threadIdx.x & 63;
    int lm = l & 15, lh = l >> 4;
    int b0 = mb * 16;
    int c  = nc * 64 + w * 16 + lm;   // this lane's fused output column
    bool isH = (nc < 16);

    __shared__ float lt[4][16][17];   // per-wave transpose tile

    // prologue: register-resident weight fragments (one-time global reads)
    f16x8 bw[32];
    #pragma unroll
    for (int kt = 0; kt < 32; ++kt)
        bw[kt] = *reinterpret_cast<const f16x8*>(Wr + (size_t)c * 1024 + kt*32 + lh*8);

    for (int t = 0; t < T_LEN; ++t) {
        const f16* hin = hP + (size_t)(t & 1) * 65536;
        f32x4 a0 = (f32x4){0.f,0.f,0.f,0.f};
        f32x4 a1 = (f32x4){0.f,0.f,0.f,0.f};
        #pragma unroll
        for (int kt = 0; kt < 32; ++kt) {
            f16x8 af = *reinterpret_cast<const f16x8*>(
                hin + ((size_t)(kt*4 + lh)*64 + b0 + lm) * 8);
            if (kt & 1) a1 = __builtin_amdgcn_mfma_f32_16x16x32_f16(af, bw[kt], a1, 0, 0, 0);
            else        a0 = __builtin_amdgcn_mfma_f32_16x16x32_f16(af, bw[kt], a0, 0, 0, 0);
        }
        f32x4 acc = a0 + a1;

        // write acc into per-wave LDS tile: lt[w][b_local][c_local]
        #pragma unroll
        for (int r = 0; r < 4; ++r)
            lt[w][lh*4 + r][lm] = acc[r];
        __syncthreads();

        if (isH) {
            // lanes 0..31: b = l&15, cb = l>>4 (two 8-col blocks)
            if (l < 32) {
                int b = l & 15, cb = l >> 4;
                int cblk = nc*8 + w*2 + cb;
                f16x8 xv = *reinterpret_cast<const f16x8*>(
                    Xh + ((size_t)t*8192 + (size_t)cblk*64 + b0 + b)*8);
                f16x8 hv;
                #pragma unroll
                for (int e = 0; e < 8; ++e)
                    hv[e] = (f16)(lt[w][b][cb*8 + e] + (float)xv[e]);
                *reinterpret_cast<f16x8*>(
                    hP + (size_t)((t+1)&1)*65536 + ((size_t)cblk*64 + b0 + b)*8) = hv;
            }
        } else {
            // all 64 lanes: b = l&15, cq = l>>4 (four 4-col quads)
            int b = l & 15, cq = l >> 4;
            size_t oidx = ((size_t)(b0+b)*512 + t)*1024 + (size_t)(nc-16)*64 + w*16 + cq*4;
            f32x4 ov = *reinterpret_cast<f32x4*>(Out + oidx);
            #pragma unroll
            for (int e = 0; e < 4; ++e)
                ov[e] += lt[w][b][cq*4 + e];
            *reinterpret_cast<f32x4*>(Out + oidx) = ov;
        }

        __threadfence();
        grid.sync();
    }
}

// ---------- workspace layout (bytes) ----------
// [0, 4M)    Wx f16 [2048][1024]
// [4M, 8M)   Wr f16 [2048][1024]
// [8M, 72M)  Xh f16 packed [512][128][64][8]
// [72M, ..)  hP f16 [2][128][64][8]  (256 KB)

extern "C" void kernel_launch(void* const* d_in, const int* in_sizes, int n_in,
                              void* d_out, int out_size, void* d_ws, size_t ws_size,
                              hipStream_t stream) {
    const float* X  = (const float*)d_in[0];
    const float* H0 = (const float*)d_in[1];
    const float* Wh = (const float*)d_in[2];
    const float* bh = (const float*)d_in[3];
    const float* Wo = (const float*)d_in[4];
    const float* bo = (const float*)d_in[5];
    float* Out = (float*)d_out;

    char* ws = (char*)d_ws;
    f16* Wx = (f16*)(ws);
    f16* Wr = (f16*)(ws + (size_t)4*1024*1024);
    f16* Xh = (f16*)(ws + (size_t)8*1024*1024);
    f16* hP = (f16*)(ws + (size_t)8*1024*1024 + (size_t)M_TOT*1024*2);

    hipLaunchKernelGGL(k_prep_w, dim3(2048), dim3(256), 0, stream, Wh, Wo, Wx, Wr);
    hipLaunchKernelGGL(k_init_h, dim3(32), dim3(256), 0, stream, H0, hP);
    hipLaunchKernelGGL(k_gemm1, dim3(256, 16), dim3(256), 0, stream, X, Wx, bh, bo, Xh, Out);

    void* args[] = { (void*)&Wr, (void*)&Xh, (void*)&hP, (void*)&Out };
    hipLaunchCooperativeKernel((const void*)k_rnn, dim3(128), dim3(256), args, 0, stream);
}

// Round 3
// 11230.442 us; speedup vs baseline: 1.5008x; 1.5008x over previous
//
#include <hip/hip_runtime.h>
#include <hip/hip_bf16.h>

// RNNLayer: B=64, T=512, D_IN=D_H=D_OUT=1024.
// h_{t+1} = x_t@Wxh^T + h_t@Wrh^T + bh ; o_t = x_t@Wxo^T + h_t@Wro^T + bo
// Phase 1: Xh = X@Wxh^T + bh (packed), Out = X@Wxo^T + bo   (parallel GEMM)
// Phase 2: 16-WG persistent h-chain, hand-rolled flag barrier, h history -> Hs
// Phase 3: Out += Hs@Wro^T                                   (parallel GEMM)

typedef _Float16 f16;
typedef _Float16 f16x8 __attribute__((ext_vector_type(8)));
typedef _Float16 f16x4 __attribute__((ext_vector_type(4)));
typedef float f32x4 __attribute__((ext_vector_type(4)));

#define T_LEN 512
#define BATCH 64
#define M_TOT (BATCH * T_LEN)   // 32768
#define NWG_RNN 16

// ---------- prep: stacked fp16 weights ----------
// Wx[n][k] = W(n)[k] (input half); Wr[n][k] = W(n)[1024+k] (recurrent half)
// rows n<1024 -> W_h row n ; n>=1024 -> W_o row n-1024
__global__ void k_prep_w(const float* __restrict__ Wh, const float* __restrict__ Wo,
                         f16* __restrict__ Wx, f16* __restrict__ Wr) {
    int n = blockIdx.x;              // 0..2047
    int t4 = threadIdx.x * 4;        // 0..1020
    const float* src = (n < 1024) ? (Wh + (size_t)n * 2048)
                                  : (Wo + (size_t)(n - 1024) * 2048);
    float4 a = *reinterpret_cast<const float4*>(src + t4);
    float4 b = *reinterpret_cast<const float4*>(src + 1024 + t4);
    f16x4 va, vb;
    va[0]=(f16)a.x; va[1]=(f16)a.y; va[2]=(f16)a.z; va[3]=(f16)a.w;
    vb[0]=(f16)b.x; vb[1]=(f16)b.y; vb[2]=(f16)b.z; vb[3]=(f16)b.w;
    *reinterpret_cast<f16x4*>(Wx + (size_t)n*1024 + t4) = va;
    *reinterpret_cast<f16x4*>(Wr + (size_t)n*1024 + t4) = vb;
}

// ---------- init: Hs[0] (packed [kblk128][b64][8]) from H0, zero flags ----------
__global__ void k_init_h(const float* __restrict__ H0, f16* __restrict__ Hs) {
    int tid = blockIdx.x * 256 + threadIdx.x;   // 8192
    int b = tid >> 7, kb = tid & 127;
    float4 x0 = *reinterpret_cast<const float4*>(H0 + (size_t)b*1024 + kb*8);
    float4 x1 = *reinterpret_cast<const float4*>(H0 + (size_t)b*1024 + kb*8 + 4);
    f16x8 v;
    v[0]=(f16)x0.x; v[1]=(f16)x0.y; v[2]=(f16)x0.z; v[3]=(f16)x0.w;
    v[4]=(f16)x1.x; v[5]=(f16)x1.y; v[6]=(f16)x1.z; v[7]=(f16)x1.w;
    *reinterpret_cast<f16x8*>(Hs + ((size_t)kb*64 + b)*8) = v;
}

__global__ void k_zero_flags(unsigned int* __restrict__ flags) {
    flags[threadIdx.x] = 0;   // 512 entries (16 flags spaced 32 u32 apart)
}

// ---------- phase 1: input projection GEMM ----------
// A = X f32 [32768][1024] (rows m = b*512+t), B = Wx f16 [2048][1024]
// n<1024:  Xh packed [t][cblk128][b64][8] f16 = dot + bh
// n>=1024: Out[b][t][n-1024] f32 = dot + bo
__global__ __launch_bounds__(256) void k_gemm1(
    const float* __restrict__ Af, const f16* __restrict__ Bm,
    const float* __restrict__ bh, const float* __restrict__ bo,
    f16* __restrict__ Xh, float* __restrict__ Out)
{
    __shared__ f16 As[128][40];
    __shared__ f16 Bs[128][40];
    int m0 = blockIdx.x * 128;
    int n0 = blockIdx.y * 128;
    int t = threadIdx.x;
    int l = t & 63, wid = t >> 6;
    int wm = wid >> 1, wn = wid & 1;
    int lm = l & 15, lh = l >> 4;

    f32x4 acc[4][4];
    #pragma unroll
    for (int i = 0; i < 4; i++)
        #pragma unroll
        for (int j = 0; j < 4; j++) acc[i][j] = (f32x4){0.f,0.f,0.f,0.f};

    for (int kt = 0; kt < 32; ++kt) {
        int k0 = kt * 32;
        __syncthreads();
        #pragma unroll
        for (int c = t; c < 1024; c += 256) {
            int row = c >> 3, q = c & 7;
            float4 a = *reinterpret_cast<const float4*>(Af + (size_t)(m0+row)*1024 + k0 + q*4);
            f16x4 v; v[0]=(f16)a.x; v[1]=(f16)a.y; v[2]=(f16)a.z; v[3]=(f16)a.w;
            *reinterpret_cast<f16x4*>(&As[row][q*4]) = v;
        }
        #pragma unroll
        for (int c = t; c < 512; c += 256) {
            int row = c >> 2, q = c & 3;
            *reinterpret_cast<float4*>(&Bs[row][q*8]) =
                *reinterpret_cast<const float4*>(Bm + (size_t)(n0+row)*1024 + k0 + q*8);
        }
        __syncthreads();

        f16x8 af[4], bf[4];
        #pragma unroll
        for (int i = 0; i < 4; i++)
            af[i] = *reinterpret_cast<const f16x8*>(&As[64*wm + 16*i + lm][8*lh]);
        #pragma unroll
        for (int j = 0; j < 4; j++)
            bf[j] = *reinterpret_cast<const f16x8*>(&Bs[64*wn + 16*j + lm][8*lh]);
        #pragma unroll
        for (int i = 0; i < 4; i++)
            #pragma unroll
            for (int j = 0; j < 4; j++)
                acc[i][j] = __builtin_amdgcn_mfma_f32_16x16x32_f16(af[i], bf[j], acc[i][j], 0, 0, 0);
    }

    int r0 = lh * 4;
    bool isH = (n0 < 1024);
    #pragma unroll
    for (int i = 0; i < 4; i++)
        #pragma unroll
        for (int j = 0; j < 4; j++) {
            int gmb = m0 + 64*wm + 16*i + r0;
            int gn  = n0 + 64*wn + 16*j + lm;
            #pragma unroll
            for (int r = 0; r < 4; r++) {
                float v = acc[i][j][r];
                int gm = gmb + r;
                if (isH) {
                    int tt = gm & 511, bb = gm >> 9;
                    Xh[((size_t)tt*8192 + (size_t)(gn>>3)*64 + bb)*8 + (gn&7)] = (f16)(v + bh[gn]);
                } else {
                    Out[(size_t)gm*1024 + (gn - 1024)] = v + bo[gn - 1024];
                }
            }
        }
}

// ---------- phase 2: persistent h-chain ----------
// 16 WGs x 256 thr. Wave w of WG wg owns cols wg*64 + w*16 .. +16 (K=1024,
// Wrh slice in 128 VGPRs), all 64 batch. Per step: 128 MFMAs.
// Hs: [512][128][64][8] f16 — slab t = packed h_t. Step t: read slab t,
// write slab t+1 (+= Xh[t]). Flag barrier per step.
__global__ __launch_bounds__(256, 1) void k_rnn2(
    const f16* __restrict__ Wr,       // [2048][1024]; rows 0..1023 = Wrh
    const f16* __restrict__ Xh,       // [512][128][64][8]
    f16* __restrict__ Hs,             // [512][128][64][8]
    unsigned int* __restrict__ flags) // 16 flags, 128B apart
{
    int wg = blockIdx.x;
    int w  = threadIdx.x >> 6;
    int l  = threadIdx.x & 63;
    int lm = l & 15, lh = l >> 4;
    int c  = wg * 64 + w * 16 + lm;     // this lane's h column (B-frag row)

    __shared__ float lt[4][64][17];     // per-wave transpose tile

    // register-resident recurrent weights: 16 cols x K=1024
    f16x8 bw[32];
    #pragma unroll
    for (int kt = 0; kt < 32; ++kt)
        bw[kt] = *reinterpret_cast<const f16x8*>(Wr + (size_t)c * 1024 + kt*32 + lh*8);

    for (int t = 0; t < T_LEN - 1; ++t) {
        const f16* hin = Hs + (size_t)t * 65536;
        f16*       hout = Hs + (size_t)(t + 1) * 65536;

        // prefetch this step's Xh slice (consumed in epilogue)
        f16x8 xv[2];
        #pragma unroll
        for (int cb = 0; cb < 2; ++cb) {
            int cblk = wg*8 + w*2 + cb;
            xv[cb] = *reinterpret_cast<const f16x8*>(
                Xh + ((size_t)t*8192 + (size_t)cblk*64 + l)*8);
        }

        f32x4 acc[4];
        #pragma unroll
        for (int m = 0; m < 4; ++m) acc[m] = (f32x4){0.f,0.f,0.f,0.f};

        #pragma unroll 8
        for (int kt = 0; kt < 32; ++kt) {
            f16x8 af[4];
            #pragma unroll
            for (int m = 0; m < 4; ++m)
                af[m] = *reinterpret_cast<const f16x8*>(
                    hin + ((size_t)(kt*4 + lh)*64 + m*16 + lm)*8);
            #pragma unroll
            for (int m = 0; m < 4; ++m)
                acc[m] = __builtin_amdgcn_mfma_f32_16x16x32_f16(af[m], bw[kt], acc[m], 0, 0, 0);
        }

        // transpose through wave-private LDS tile: lt[w][batch][col_local]
        #pragma unroll
        for (int m = 0; m < 4; ++m)
            #pragma unroll
            for (int r = 0; r < 4; ++r)
                lt[w][m*16 + lh*4 + r][lm] = acc[m][r];
        // wave-private RAW: compiler inserts lgkmcnt; no __syncthreads needed

        // epilogue: lane l owns batch b=l, 16 cols -> two f16x8 vector stores
        #pragma unroll
        for (int cb = 0; cb < 2; ++cb) {
            int cblk = wg*8 + w*2 + cb;
            f16x8 hv;
            #pragma unroll
            for (int e = 0; e < 8; ++e)
                hv[e] = (f16)(lt[w][l][cb*8 + e] + (float)xv[cb][e]);
            *reinterpret_cast<f16x8*>(hout + ((size_t)cblk*64 + l)*8) = hv;
        }

        // ---- flag barrier ----
        __builtin_amdgcn_fence(__ATOMIC_RELEASE, "agent");   // flush h writes
        __syncthreads();
        if (threadIdx.x == 0)
            __hip_atomic_store(&flags[wg*32], (unsigned int)(t+1),
                               __ATOMIC_RELEASE, __HIP_MEMORY_SCOPE_AGENT);
        unsigned int tgt = (unsigned int)(t+1);
        if (l < NWG_RNN) {
            unsigned int* fp = &flags[l*32];
            while (__hip_atomic_load(fp, __ATOMIC_RELAXED, __HIP_MEMORY_SCOPE_AGENT) < tgt)
                __builtin_amdgcn_s_sleep(1);
        }
        __builtin_amdgcn_fence(__ATOMIC_ACQUIRE, "agent");   // see remote h writes
    }
}

// ---------- phase 3: output GEMM  Out += Hs @ Wro^T ----------
// A = Hs packed [512][128][64][8] (row m' = t*64+b), B = Wr rows 1024..2047
__global__ __launch_bounds__(256) void k_gemm2(
    const f16* __restrict__ Hs, const f16* __restrict__ Bm, float* __restrict__ Out)
{
    __shared__ f16 As[128][40];
    __shared__ f16 Bs[128][40];
    int m0 = blockIdx.x * 128;          // m' = t*64 + b
    int n0 = blockIdx.y * 128;          // 0..896
    int t = threadIdx.x;
    int l = t & 63, wid = t >> 6;
    int wm = wid >> 1, wn = wid & 1;
    int lm = l & 15, lh = l >> 4;

    f32x4 acc[4][4];
    #pragma unroll
    for (int i = 0; i < 4; i++)
        #pragma unroll
        for (int j = 0; j < 4; j++) acc[i][j] = (f32x4){0.f,0.f,0.f,0.f};

    for (int kt = 0; kt < 32; ++kt) {
        __syncthreads();
        // A: 512 chunks of 16B; q = c>>7 (k-sub), r = c&127 (row) -> bb contiguous
        #pragma unroll
        for (int c = t; c < 512; c += 256) {
            int q = c >> 7, r = c & 127;
            int tt = (m0 + r) >> 6, bb = r & 63;
            *reinterpret_cast<float4*>(&As[r][q*8]) =
                *reinterpret_cast<const float4*>(Hs + ((size_t)tt*8192 + (size_t)(kt*4+q)*64 + bb)*8);
        }
        #pragma unroll
        for (int c = t; c < 512; c += 256) {
            int row = c >> 2, q = c & 3;
            *reinterpret_cast<float4*>(&Bs[row][q*8]) =
                *reinterpret_cast<const float4*>(Bm + (size_t)(n0+row)*1024 + kt*32 + q*8);
        }
        __syncthreads();

        f16x8 af[4], bf[4];
        #pragma unroll
        for (int i = 0; i < 4; i++)
            af[i] = *reinterpret_cast<const f16x8*>(&As[64*wm + 16*i + lm][8*lh]);
        #pragma unroll
        for (int j = 0; j < 4; j++)
            bf[j] = *reinterpret_cast<const f16x8*>(&Bs[64*wn + 16*j + lm][8*lh]);
        #pragma unroll
        for (int i = 0; i < 4; i++)
            #pragma unroll
            for (int j = 0; j < 4; j++)
                acc[i][j] = __builtin_amdgcn_mfma_f32_16x16x32_f16(af[i], bf[j], acc[i][j], 0, 0, 0);
    }

    int r0 = lh * 4;
    #pragma unroll
    for (int i = 0; i < 4; i++)
        #pragma unroll
        for (int j = 0; j < 4; j++) {
            int gmb = m0 + 64*wm + 16*i + r0;
            int gn  = n0 + 64*wn + 16*j + lm;
            #pragma unroll
            for (int r = 0; r < 4; r++) {
                int gm = gmb + r;               // m' = t*64 + b
                int bb = gm & 63, tt = gm >> 6;
                size_t o = ((size_t)bb*512 + tt)*1024 + gn;
                Out[o] += acc[i][j][r];
            }
        }
}

// ---------- workspace layout (bytes) ----------
// [0, 4M)        Wx f16 [2048][1024]
// [4M, 8M)       Wr f16 [2048][1024]   (rows 0..1023 = Wrh, 1024..2047 = Wro)
// [8M, 72M)      Xh f16 packed [512][128][64][8]
// [72M, 136M)    Hs f16 packed [512][128][64][8]
// [136M, +2K)    flags u32[512]
// total ~136.3 MB

extern "C" void kernel_launch(void* const* d_in, const int* in_sizes, int n_in,
                              void* d_out, int out_size, void* d_ws, size_t ws_size,
                              hipStream_t stream) {
    const float* X  = (const float*)d_in[0];
    const float* H0 = (const float*)d_in[1];
    const float* Wh = (const float*)d_in[2];
    const float* bh = (const float*)d_in[3];
    const float* Wo = (const float*)d_in[4];
    const float* bo = (const float*)d_in[5];
    float* Out = (float*)d_out;

    char* ws = (char*)d_ws;
    f16* Wx = (f16*)(ws);
    f16* Wr = (f16*)(ws + (size_t)4*1024*1024);
    f16* Xh = (f16*)(ws + (size_t)8*1024*1024);
    f16* Hs = (f16*)(ws + (size_t)8*1024*1024 + (size_t)M_TOT*1024*2);
    unsigned int* flags = (unsigned int*)(ws + (size_t)8*1024*1024 + (size_t)2*M_TOT*1024*2);

    hipLaunchKernelGGL(k_prep_w, dim3(2048), dim3(256), 0, stream, Wh, Wo, Wx, Wr);
    hipLaunchKernelGGL(k_init_h, dim3(32), dim3(256), 0, stream, H0, Hs);
    hipLaunchKernelGGL(k_zero_flags, dim3(1), dim3(512), 0, stream, flags);
    hipLaunchKernelGGL(k_gemm1, dim3(256, 16), dim3(256), 0, stream, X, Wx, bh, bo, Xh, Out);

    void* args[] = { (void*)&Wr, (void*)&Xh, (void*)&Hs, (void*)&flags };
    hipLaunchCooperativeKernel((const void*)k_rnn2, dim3(NWG_RNN), dim3(256), args, 0, stream);

    f16* Wro = Wr + (size_t)1024*1024;
    hipLaunchKernelGGL(k_gemm2, dim3(256, 8), dim3(256), 0, stream, Hs, Wro, Out);
}

// Round 4
// 9682.168 us; speedup vs baseline: 1.7408x; 1.1599x over previous
//
#include <hip/hip_runtime.h>
#include <hip/hip_bf16.h>

// RNNLayer: B=64, T=512, D_IN=D_H=D_OUT=1024.
// h_{t+1} = x_t@Wxh^T + h_t@Wrh^T + bh ; o_t = x_t@Wxo^T + h_t@Wro^T + bo
// Phase 1: Xh = X@Wxh^T + bh (packed), Out = X@Wxo^T + bo   (parallel GEMM)
// Phase 2: 16-WG persistent h-chain, minimal flag barrier, h history -> Hs
//          (weights pinned in VGPRs via asm; writer-side wbl2 only, no inv)
// Phase 3: Out += Hs@Wro^T                                   (parallel GEMM)

typedef _Float16 f16;
typedef _Float16 f16x8 __attribute__((ext_vector_type(8)));
typedef _Float16 f16x4 __attribute__((ext_vector_type(4)));
typedef float f32x4 __attribute__((ext_vector_type(4)));

#define T_LEN 512
#define BATCH 64
#define M_TOT (BATCH * T_LEN)   // 32768
#define NWG_RNN 16

// ---------- prep: stacked fp16 weights ----------
__global__ void k_prep_w(const float* __restrict__ Wh, const float* __restrict__ Wo,
                         f16* __restrict__ Wx, f16* __restrict__ Wr) {
    int n = blockIdx.x;              // 0..2047
    int t4 = threadIdx.x * 4;        // 0..1020
    const float* src = (n < 1024) ? (Wh + (size_t)n * 2048)
                                  : (Wo + (size_t)(n - 1024) * 2048);
    float4 a = *reinterpret_cast<const float4*>(src + t4);
    float4 b = *reinterpret_cast<const float4*>(src + 1024 + t4);
    f16x4 va, vb;
    va[0]=(f16)a.x; va[1]=(f16)a.y; va[2]=(f16)a.z; va[3]=(f16)a.w;
    vb[0]=(f16)b.x; vb[1]=(f16)b.y; vb[2]=(f16)b.z; vb[3]=(f16)b.w;
    *reinterpret_cast<f16x4*>(Wx + (size_t)n*1024 + t4) = va;
    *reinterpret_cast<f16x4*>(Wr + (size_t)n*1024 + t4) = vb;
}

// ---------- init: Hs[0] (packed [kblk128][b64][8]) from H0 ----------
__global__ void k_init_h(const float* __restrict__ H0, f16* __restrict__ Hs) {
    int tid = blockIdx.x * 256 + threadIdx.x;   // 8192
    int b = tid >> 7, kb = tid & 127;
    float4 x0 = *reinterpret_cast<const float4*>(H0 + (size_t)b*1024 + kb*8);
    float4 x1 = *reinterpret_cast<const float4*>(H0 + (size_t)b*1024 + kb*8 + 4);
    f16x8 v;
    v[0]=(f16)x0.x; v[1]=(f16)x0.y; v[2]=(f16)x0.z; v[3]=(f16)x0.w;
    v[4]=(f16)x1.x; v[5]=(f16)x1.y; v[6]=(f16)x1.z; v[7]=(f16)x1.w;
    *reinterpret_cast<f16x8*>(Hs + ((size_t)kb*64 + b)*8) = v;
}

__global__ void k_zero_flags(unsigned int* __restrict__ flags) {
    flags[threadIdx.x] = 0;   // 512 entries (16 flags spaced 32 u32 apart)
}

// ---------- phase 1: input projection GEMM ----------
__global__ __launch_bounds__(256) void k_gemm1(
    const float* __restrict__ Af, const f16* __restrict__ Bm,
    const float* __restrict__ bh, const float* __restrict__ bo,
    f16* __restrict__ Xh, float* __restrict__ Out)
{
    __shared__ f16 As[128][40];
    __shared__ f16 Bs[128][40];
    int m0 = blockIdx.x * 128;
    int n0 = blockIdx.y * 128;
    int t = threadIdx.x;
    int l = t & 63, wid = t >> 6;
    int wm = wid >> 1, wn = wid & 1;
    int lm = l & 15, lh = l >> 4;

    f32x4 acc[4][4];
    #pragma unroll
    for (int i = 0; i < 4; i++)
        #pragma unroll
        for (int j = 0; j < 4; j++) acc[i][j] = (f32x4){0.f,0.f,0.f,0.f};

    for (int kt = 0; kt < 32; ++kt) {
        int k0 = kt * 32;
        __syncthreads();
        #pragma unroll
        for (int c = t; c < 1024; c += 256) {
            int row = c >> 3, q = c & 7;
            float4 a = *reinterpret_cast<const float4*>(Af + (size_t)(m0+row)*1024 + k0 + q*4);
            f16x4 v; v[0]=(f16)a.x; v[1]=(f16)a.y; v[2]=(f16)a.z; v[3]=(f16)a.w;
            *reinterpret_cast<f16x4*>(&As[row][q*4]) = v;
        }
        #pragma unroll
        for (int c = t; c < 512; c += 256) {
            int row = c >> 2, q = c & 3;
            *reinterpret_cast<float4*>(&Bs[row][q*8]) =
                *reinterpret_cast<const float4*>(Bm + (size_t)(n0+row)*1024 + k0 + q*8);
        }
        __syncthreads();

        f16x8 af[4], bf[4];
        #pragma unroll
        for (int i = 0; i < 4; i++)
            af[i] = *reinterpret_cast<const f16x8*>(&As[64*wm + 16*i + lm][8*lh]);
        #pragma unroll
        for (int j = 0; j < 4; j++)
            bf[j] = *reinterpret_cast<const f16x8*>(&Bs[64*wn + 16*j + lm][8*lh]);
        #pragma unroll
        for (int i = 0; i < 4; i++)
            #pragma unroll
            for (int j = 0; j < 4; j++)
                acc[i][j] = __builtin_amdgcn_mfma_f32_16x16x32_f16(af[i], bf[j], acc[i][j], 0, 0, 0);
    }

    int r0 = lh * 4;
    bool isH = (n0 < 1024);
    #pragma unroll
    for (int i = 0; i < 4; i++)
        #pragma unroll
        for (int j = 0; j < 4; j++) {
            int gmb = m0 + 64*wm + 16*i + r0;
            int gn  = n0 + 64*wn + 16*j + lm;
            #pragma unroll
            for (int r = 0; r < 4; r++) {
                float v = acc[i][j][r];
                int gm = gmb + r;
                if (isH) {
                    int tt = gm & 511, bb = gm >> 9;
                    Xh[((size_t)tt*8192 + (size_t)(gn>>3)*64 + bb)*8 + (gn&7)] = (f16)(v + bh[gn]);
                } else {
                    Out[(size_t)gm*1024 + (gn - 1024)] = v + bo[gn - 1024];
                }
            }
        }
}

// ---------- phase 2: persistent h-chain ----------
// 16 WGs x 256 thr. Wave w of WG wg owns cols wg*64 + w*16 .. +16 (K=1024,
// Wrh slice pinned in 128 VGPRs), all 64 batch. Per step: 128 MFMAs.
// Hs slabs advance t -> t+1: no address is ever re-read across steps, so the
// reader side needs NO cache invalidate; writer side needs one wbl2 before
// the flag store (thread 0 only).
__global__ __launch_bounds__(256, 1) void k_rnn2(
    const f16* __restrict__ Wr,       // [2048][1024]; rows 0..1023 = Wrh
    const f16* __restrict__ Xh,       // [512][128][64][8]
    f16* __restrict__ Hs,             // [512][128][64][8]
    unsigned int* __restrict__ flags) // 16 flags, 128B apart
{
    int wg = blockIdx.x;
    int w  = threadIdx.x >> 6;
    int l  = threadIdx.x & 63;
    int lm = l & 15, lh = l >> 4;
    int c  = wg * 64 + w * 16 + lm;     // this lane's h column (B-frag row)

    __shared__ float lt[4][64][17];     // per-wave transpose tile

    // register-resident recurrent weights: 16 cols x K=1024 = 128 VGPRs/lane
    f16x8 bw[32];
    #pragma unroll
    for (int kt = 0; kt < 32; ++kt)
        bw[kt] = *reinterpret_cast<const f16x8*>(Wr + (size_t)c * 1024 + kt*32 + lh*8);
    // pin: values become asm-defined -> compiler cannot rematerialize the loads
    #pragma unroll
    for (int kt = 0; kt < 32; ++kt)
        asm volatile("" : "+v"(bw[kt]));

    for (int t = 0; t < T_LEN - 1; ++t) {
        const f16* hin  = Hs + (size_t)t * 65536;
        f16*       hout = Hs + (size_t)(t + 1) * 65536;

        // prefetch this step's Xh slice (consumed in epilogue)
        f16x8 xv[2];
        #pragma unroll
        for (int cb = 0; cb < 2; ++cb) {
            int cblk = wg*8 + w*2 + cb;
            xv[cb] = *reinterpret_cast<const f16x8*>(
                Xh + ((size_t)t*8192 + (size_t)cblk*64 + l)*8);
        }

        f32x4 acc[4];
        #pragma unroll
        for (int m = 0; m < 4; ++m) acc[m] = (f32x4){0.f,0.f,0.f,0.f};

        #pragma unroll 8
        for (int kt = 0; kt < 32; ++kt) {
            f16x8 af[4];
            #pragma unroll
            for (int m = 0; m < 4; ++m)
                af[m] = *reinterpret_cast<const f16x8*>(
                    hin + ((size_t)(kt*4 + lh)*64 + m*16 + lm)*8);
            #pragma unroll
            for (int m = 0; m < 4; ++m)
                acc[m] = __builtin_amdgcn_mfma_f32_16x16x32_f16(af[m], bw[kt], acc[m], 0, 0, 0);
        }

        // transpose through wave-private LDS tile: lt[w][batch][col_local]
        #pragma unroll
        for (int m = 0; m < 4; ++m)
            #pragma unroll
            for (int r = 0; r < 4; ++r)
                lt[w][m*16 + lh*4 + r][lm] = acc[m][r];
        // wave-private RAW: compiler inserts lgkmcnt; no __syncthreads needed

        // epilogue: lane l owns batch b=l, 16 cols -> two f16x8 vector stores
        #pragma unroll
        for (int cb = 0; cb < 2; ++cb) {
            int cblk = wg*8 + w*2 + cb;
            f16x8 hv;
            #pragma unroll
            for (int e = 0; e < 8; ++e)
                hv[e] = (f16)(lt[w][l][cb*8 + e] + (float)xv[cb][e]);
            *reinterpret_cast<f16x8*>(hout + ((size_t)cblk*64 + l)*8) = hv;
        }

        // ---- minimal flag barrier ----
        // every wave: drain its stores to L2
        asm volatile("s_waitcnt vmcnt(0)" ::: "memory");
        __syncthreads();
        // single thread: flush L2 -> L3, then publish flag (agent, bypasses L2)
        if (threadIdx.x == 0) {
            __builtin_amdgcn_fence(__ATOMIC_RELEASE, "agent");
            __hip_atomic_store(&flags[wg*32], (unsigned int)(t+1),
                               __ATOMIC_RELAXED, __HIP_MEMORY_SCOPE_AGENT);
        }
        // wave 0 polls all 16 flags (one per lane); reconverges when all done
        if (threadIdx.x < NWG_RNN) {
            unsigned int tgt = (unsigned int)(t+1);
            unsigned int* fp = &flags[threadIdx.x*32];
            while (__hip_atomic_load(fp, __ATOMIC_RELAXED, __HIP_MEMORY_SCOPE_AGENT) < tgt)
                __builtin_amdgcn_s_sleep(1);
        }
        __syncthreads();
        // compiler-only barrier: forbid hoisting next step's loads above the poll
        asm volatile("" ::: "memory");
    }
}

// ---------- phase 3: output GEMM  Out += Hs @ Wro^T ----------
__global__ __launch_bounds__(256) void k_gemm2(
    const f16* __restrict__ Hs, const f16* __restrict__ Bm, float* __restrict__ Out)
{
    __shared__ f16 As[128][40];
    __shared__ f16 Bs[128][40];
    int m0 = blockIdx.x * 128;          // m' = t*64 + b
    int n0 = blockIdx.y * 128;          // 0..896
    int t = threadIdx.x;
    int l = t & 63, wid = t >> 6;
    int wm = wid >> 1, wn = wid & 1;
    int lm = l & 15, lh = l >> 4;

    f32x4 acc[4][4];
    #pragma unroll
    for (int i = 0; i < 4; i++)
        #pragma unroll
        for (int j = 0; j < 4; j++) acc[i][j] = (f32x4){0.f,0.f,0.f,0.f};

    for (int kt = 0; kt < 32; ++kt) {
        __syncthreads();
        #pragma unroll
        for (int c = t; c < 512; c += 256) {
            int q = c >> 7, r = c & 127;
            int tt = (m0 + r) >> 6, bb = r & 63;
            *reinterpret_cast<float4*>(&As[r][q*8]) =
                *reinterpret_cast<const float4*>(Hs + ((size_t)tt*8192 + (size_t)(kt*4+q)*64 + bb)*8);
        }
        #pragma unroll
        for (int c = t; c < 512; c += 256) {
            int row = c >> 2, q = c & 3;
            *reinterpret_cast<float4*>(&Bs[row][q*8]) =
                *reinterpret_cast<const float4*>(Bm + (size_t)(n0+row)*1024 + kt*32 + q*8);
        }
        __syncthreads();

        f16x8 af[4], bf[4];
        #pragma unroll
        for (int i = 0; i < 4; i++)
            af[i] = *reinterpret_cast<const f16x8*>(&As[64*wm + 16*i + lm][8*lh]);
        #pragma unroll
        for (int j = 0; j < 4; j++)
            bf[j] = *reinterpret_cast<const f16x8*>(&Bs[64*wn + 16*j + lm][8*lh]);
        #pragma unroll
        for (int i = 0; i < 4; i++)
            #pragma unroll
            for (int j = 0; j < 4; j++)
                acc[i][j] = __builtin_amdgcn_mfma_f32_16x16x32_f16(af[i], bf[j], acc[i][j], 0, 0, 0);
    }

    int r0 = lh * 4;
    #pragma unroll
    for (int i = 0; i < 4; i++)
        #pragma unroll
        for (int j = 0; j < 4; j++) {
            int gmb = m0 + 64*wm + 16*i + r0;
            int gn  = n0 + 64*wn + 16*j + lm;
            #pragma unroll
            for (int r = 0; r < 4; r++) {
                int gm = gmb + r;               // m' = t*64 + b
                int bb = gm & 63, tt = gm >> 6;
                size_t o = ((size_t)bb*512 + tt)*1024 + gn;
                Out[o] += acc[i][j][r];
            }
        }
}

// ---------- workspace layout (bytes) ----------
// [0, 4M)        Wx f16 [2048][1024]
// [4M, 8M)       Wr f16 [2048][1024]   (rows 0..1023 = Wrh, 1024..2047 = Wro)
// [8M, 72M)      Xh f16 packed [512][128][64][8]
// [72M, 136M)    Hs f16 packed [512][128][64][8]
// [136M, +2K)    flags u32[512]

extern "C" void kernel_launch(void* const* d_in, const int* in_sizes, int n_in,
                              void* d_out, int out_size, void* d_ws, size_t ws_size,
                              hipStream_t stream) {
    const float* X  = (const float*)d_in[0];
    const float* H0 = (const float*)d_in[1];
    const float* Wh = (const float*)d_in[2];
    const float* bh = (const float*)d_in[3];
    const float* Wo = (const float*)d_in[4];
    const float* bo = (const float*)d_in[5];
    float* Out = (float*)d_out;

    char* ws = (char*)d_ws;
    f16* Wx = (f16*)(ws);
    f16* Wr = (f16*)(ws + (size_t)4*1024*1024);
    f16* Xh = (f16*)(ws + (size_t)8*1024*1024);
    f16* Hs = (f16*)(ws + (size_t)8*1024*1024 + (size_t)M_TOT*1024*2);
    unsigned int* flags = (unsigned int*)(ws + (size_t)8*1024*1024 + (size_t)2*M_TOT*1024*2);

    hipLaunchKernelGGL(k_prep_w, dim3(2048), dim3(256), 0, stream, Wh, Wo, Wx, Wr);
    hipLaunchKernelGGL(k_init_h, dim3(32), dim3(256), 0, stream, H0, Hs);
    hipLaunchKernelGGL(k_zero_flags, dim3(1), dim3(512), 0, stream, flags);
    hipLaunchKernelGGL(k_gemm1, dim3(256, 16), dim3(256), 0, stream, X, Wx, bh, bo, Xh, Out);

    void* args[] = { (void*)&Wr, (void*)&Xh, (void*)&Hs, (void*)&flags };
    hipLaunchCooperativeKernel((const void*)k_rnn2, dim3(NWG_RNN), dim3(256), args, 0, stream);

    f16* Wro = Wr + (size_t)1024*1024;
    hipLaunchKernelGGL(k_gemm2, dim3(256, 8), dim3(256), 0, stream, Hs, Wro, Out);
}

// Round 6
// 4009.352 us; speedup vs baseline: 4.2038x; 2.4149x over previous
//
#include <hip/hip_runtime.h>
#include <hip/hip_bf16.h>

// RNNLayer: B=64, T=512, D_IN=D_H=D_OUT=1024.
// h_{t+1} = x_t@Wxh^T + h_t@Wrh^T + bh ; o_t = x_t@Wxo^T + h_t@Wro^T + bo
// Phase 1: Xh = X@Wxh^T + bh (packed), Out = X@Wxo^T + bo   (parallel GEMM)
// Phase 2: 64-WG persistent h-chain: WG=(bg:16 batch rows, cg:64 cols).
//          bg = wg>>4 so the 16 producers of a bg region are contiguous WGs
//          [bg*16, bg*16+16) — matching the flag poll (round-5 bug: bg=wg&3
//          polled the wrong producer set -> race).
// Phase 3: Out += Hs@Wro^T                                   (parallel GEMM)

typedef _Float16 f16;
typedef _Float16 f16x8 __attribute__((ext_vector_type(8)));
typedef _Float16 f16x4 __attribute__((ext_vector_type(4)));
typedef float f32x4 __attribute__((ext_vector_type(4)));
typedef int i32x4 __attribute__((ext_vector_type(4)));

#define T_LEN 512
#define BATCH 64
#define M_TOT (BATCH * T_LEN)   // 32768
#define NWG_RNN 64

// Hs/Xh slab layout (per t): [bg 4][cblk 128][b 16][8] f16 = 65536 elems
// elem(bg, cblk, b, e) = bg*16384 + cblk*128 + b*8 + e ; col = cblk*8 + e

// ---------- prep: stacked fp16 weights ----------
__global__ void k_prep_w(const float* __restrict__ Wh, const float* __restrict__ Wo,
                         f16* __restrict__ Wx, f16* __restrict__ Wr) {
    int n = blockIdx.x;              // 0..2047
    int t4 = threadIdx.x * 4;        // 0..1020
    const float* src = (n < 1024) ? (Wh + (size_t)n * 2048)
                                  : (Wo + (size_t)(n - 1024) * 2048);
    float4 a = *reinterpret_cast<const float4*>(src + t4);
    float4 b = *reinterpret_cast<const float4*>(src + 1024 + t4);
    f16x4 va, vb;
    va[0]=(f16)a.x; va[1]=(f16)a.y; va[2]=(f16)a.z; va[3]=(f16)a.w;
    vb[0]=(f16)b.x; vb[1]=(f16)b.y; vb[2]=(f16)b.z; vb[3]=(f16)b.w;
    *reinterpret_cast<f16x4*>(Wx + (size_t)n*1024 + t4) = va;
    *reinterpret_cast<f16x4*>(Wr + (size_t)n*1024 + t4) = vb;
}

// ---------- init: Hs[0] from H0 (packed layout) ----------
__global__ void k_init_h(const float* __restrict__ H0, f16* __restrict__ Hs) {
    int tid = blockIdx.x * 256 + threadIdx.x;   // 8192
    int b = tid >> 7, kb = tid & 127;           // b 0..63, cblk 0..127
    float4 x0 = *reinterpret_cast<const float4*>(H0 + (size_t)b*1024 + kb*8);
    float4 x1 = *reinterpret_cast<const float4*>(H0 + (size_t)b*1024 + kb*8 + 4);
    f16x8 v;
    v[0]=(f16)x0.x; v[1]=(f16)x0.y; v[2]=(f16)x0.z; v[3]=(f16)x0.w;
    v[4]=(f16)x1.x; v[5]=(f16)x1.y; v[6]=(f16)x1.z; v[7]=(f16)x1.w;
    size_t idx = (size_t)(b >> 4)*16384 + (size_t)kb*128 + (size_t)(b & 15)*8;
    *reinterpret_cast<f16x8*>(Hs + idx) = v;
}

__global__ void k_zero_flags(unsigned int* __restrict__ flags) {
    flags[blockIdx.x * 256 + threadIdx.x] = 0;   // 2048 u32 (64 flags, 128B apart)
}

// ---------- phase 1: input projection GEMM ----------
__global__ __launch_bounds__(256) void k_gemm1(
    const float* __restrict__ Af, const f16* __restrict__ Bm,
    const float* __restrict__ bh, const float* __restrict__ bo,
    f16* __restrict__ Xh, float* __restrict__ Out)
{
    __shared__ f16 As[128][40];
    __shared__ f16 Bs[128][40];
    int m0 = blockIdx.x * 128;
    int n0 = blockIdx.y * 128;
    int t = threadIdx.x;
    int l = t & 63, wid = t >> 6;
    int wm = wid >> 1, wn = wid & 1;
    int lm = l & 15, lh = l >> 4;

    f32x4 acc[4][4];
    #pragma unroll
    for (int i = 0; i < 4; i++)
        #pragma unroll
        for (int j = 0; j < 4; j++) acc[i][j] = (f32x4){0.f,0.f,0.f,0.f};

    for (int kt = 0; kt < 32; ++kt) {
        int k0 = kt * 32;
        __syncthreads();
        #pragma unroll
        for (int c = t; c < 1024; c += 256) {
            int row = c >> 3, q = c & 7;
            float4 a = *reinterpret_cast<const float4*>(Af + (size_t)(m0+row)*1024 + k0 + q*4);
            f16x4 v; v[0]=(f16)a.x; v[1]=(f16)a.y; v[2]=(f16)a.z; v[3]=(f16)a.w;
            *reinterpret_cast<f16x4*>(&As[row][q*4]) = v;
        }
        #pragma unroll
        for (int c = t; c < 512; c += 256) {
            int row = c >> 2, q = c & 3;
            *reinterpret_cast<float4*>(&Bs[row][q*8]) =
                *reinterpret_cast<const float4*>(Bm + (size_t)(n0+row)*1024 + k0 + q*8);
        }
        __syncthreads();

        f16x8 af[4], bf[4];
        #pragma unroll
        for (int i = 0; i < 4; i++)
            af[i] = *reinterpret_cast<const f16x8*>(&As[64*wm + 16*i + lm][8*lh]);
        #pragma unroll
        for (int j = 0; j < 4; j++)
            bf[j] = *reinterpret_cast<const f16x8*>(&Bs[64*wn + 16*j + lm][8*lh]);
        #pragma unroll
        for (int i = 0; i < 4; i++)
            #pragma unroll
            for (int j = 0; j < 4; j++)
                acc[i][j] = __builtin_amdgcn_mfma_f32_16x16x32_f16(af[i], bf[j], acc[i][j], 0, 0, 0);
    }

    int r0 = lh * 4;
    bool isH = (n0 < 1024);
    #pragma unroll
    for (int i = 0; i < 4; i++)
        #pragma unroll
        for (int j = 0; j < 4; j++) {
            int gmb = m0 + 64*wm + 16*i + r0;
            int gn  = n0 + 64*wn + 16*j + lm;
            #pragma unroll
            for (int r = 0; r < 4; r++) {
                float v = acc[i][j][r];
                int gm = gmb + r;                 // m = b*512 + t
                if (isH) {
                    int tt = gm & 511, bb = gm >> 9;
                    size_t idx = (size_t)tt*65536 + (size_t)(bb>>4)*16384
                               + (size_t)(gn>>3)*128 + (size_t)(bb&15)*8 + (gn&7);
                    Xh[idx] = (f16)(v + bh[gn]);
                } else {
                    Out[(size_t)gm*1024 + (gn - 1024)] = v + bo[gn - 1024];
                }
            }
        }
}

// ---------- phase 2: persistent h-chain, 64 WGs x 256 ----------
// WG wg: bg = wg>>4 (16 batch rows), cg = wg&15 (64 cols). Wave w: 16 cols.
// Producers of bg region = WGs [bg*16, bg*16+16)  == poll set.
// Weights: 32 x f16x8 = 128 VGPR/lane, pinned. Per wave per step: 32 MFMA.
__global__ __launch_bounds__(256, 1) void k_rnn3(
    const f16* __restrict__ Wr,       // [2048][1024]; rows 0..1023 = Wrh
    const f16* __restrict__ Xh,       // [512][bg][cblk][b][8]
    f16* __restrict__ Hs,             // [512][bg][cblk][b][8]
    unsigned int* __restrict__ flags) // 64 flags, 128B apart
{
    int wg = blockIdx.x;
    int bg = wg >> 4;                   // 0..3
    int cg = wg & 15;                   // 0..15
    int w  = threadIdx.x >> 6;
    int l  = threadIdx.x & 63;
    int lm = l & 15, lh = l >> 4;
    int c  = cg * 64 + w * 16 + lm;     // this lane's h column (B-frag row)

    __shared__ f16 hbuf[16384];         // 32 KB: staged h slab for this bg
    __shared__ float lt[4][16][17];     // per-wave transpose tile

    // register-resident recurrent weights: 16 cols x K=1024 = 128 VGPRs/lane
    f16x8 bw[32];
    #pragma unroll
    for (int kt = 0; kt < 32; ++kt)
        bw[kt] = *reinterpret_cast<const f16x8*>(Wr + (size_t)c * 1024 + kt*32 + lh*8);
    #pragma unroll
    for (int kt = 0; kt < 32; ++kt)
        asm volatile("" : "+v"(bw[kt]));

    const unsigned int bgBase = bg * 16;

    for (int t = 0; t < T_LEN - 1; ++t) {
        // Xh[t] prefetch (independent of barrier) — lanes 0..31 only
        f16x8 xv;
        int b_ep = l & 15, cb_ep = l >> 4;          // epilogue task ids
        if (l < 32) {
            int cblk = cg*8 + w*2 + cb_ep;
            xv = *reinterpret_cast<const f16x8*>(
                Xh + (size_t)t*65536 + (size_t)bg*16384 + (size_t)cblk*128 + b_ep*8);
        }

        // ---- wait for slab t (this bg's 16 producers finished step t-1) ----
        if (threadIdx.x < 16) {
            unsigned int tgt = (unsigned int)t;
            const unsigned int* fp = &flags[(bgBase + threadIdx.x) * 32];
            while (__hip_atomic_load(fp, __ATOMIC_RELAXED, __HIP_MEMORY_SCOPE_AGENT) < tgt)
                __builtin_amdgcn_s_sleep(1);
        }
        __syncthreads();
        asm volatile("" ::: "memory");

        // ---- stage slab t's bg region (32 KB) into LDS ----
        {
            const char* gsrc = (const char*)Hs + ((size_t)t*65536 + (size_t)bg*16384)*2
                             + (size_t)w*8192 + (size_t)l*16;
            char* ldst = (char*)hbuf + (size_t)w*8192;
            #pragma unroll
            for (int i = 0; i < 8; ++i)
                __builtin_amdgcn_global_load_lds(
                    (const __attribute__((address_space(1))) void*)(gsrc + i*1024),
                    (__attribute__((address_space(3))) void*)(ldst + i*1024),
                    16, 0, 0);
        }
        asm volatile("s_waitcnt vmcnt(0)" ::: "memory");
        __syncthreads();

        // ---- compute: acc[16b x 16c] = h_t[bg] @ bw^T ----
        f32x4 a0 = (f32x4){0.f,0.f,0.f,0.f};
        f32x4 a1 = (f32x4){0.f,0.f,0.f,0.f};
        #pragma unroll 8
        for (int kt = 0; kt < 32; ++kt) {
            f16x8 af = *reinterpret_cast<const f16x8*>(&hbuf[(size_t)(kt*4 + lh)*128 + lm*8]);
            if (kt & 1) a1 = __builtin_amdgcn_mfma_f32_16x16x32_f16(af, bw[kt], a1, 0, 0, 0);
            else        a0 = __builtin_amdgcn_mfma_f32_16x16x32_f16(af, bw[kt], a0, 0, 0, 0);
        }
        f32x4 acc = a0 + a1;

        // ---- transpose via wave-private LDS tile: lt[w][b][c_local] ----
        #pragma unroll
        for (int r = 0; r < 4; ++r)
            lt[w][lh*4 + r][lm] = acc[r];
        // wave-private RAW: compiler inserts lgkmcnt

        // ---- epilogue: h' = acc + Xh, sc0sc1 write-through store ----
        if (l < 32) {
            int cblk = cg*8 + w*2 + cb_ep;
            f16x8 hv;
            #pragma unroll
            for (int e = 0; e < 8; ++e)
                hv[e] = (f16)(lt[w][b_ep][cb_ep*8 + e] + (float)xv[e]);
            f16* dst = Hs + (size_t)(t+1)*65536 + (size_t)bg*16384
                     + (size_t)cblk*128 + b_ep*8;
            i32x4 iv = __builtin_bit_cast(i32x4, hv);
            asm volatile("global_store_dwordx4 %0, %1, off sc0 sc1"
                         :: "v"(dst), "v"(iv) : "memory");
        }
        asm volatile("s_waitcnt vmcnt(0)" ::: "memory");
        __syncthreads();

        // ---- publish ----
        if (threadIdx.x == 0) {
            __builtin_amdgcn_fence(__ATOMIC_RELEASE, "agent");  // cheap: L2 not dirty
            __hip_atomic_store(&flags[wg*32], (unsigned int)(t+1),
                               __ATOMIC_RELAXED, __HIP_MEMORY_SCOPE_AGENT);
        }
    }
}

// ---------- phase 3: output GEMM  Out += Hs @ Wro^T ----------
__global__ __launch_bounds__(256) void k_gemm2(
    const f16* __restrict__ Hs, const f16* __restrict__ Bm, float* __restrict__ Out)
{
    __shared__ f16 As[128][40];
    __shared__ f16 Bs[128][40];
    int m0 = blockIdx.x * 128;          // m' = t*64 + b
    int n0 = blockIdx.y * 128;          // 0..896
    int t = threadIdx.x;
    int l = t & 63, wid = t >> 6;
    int wm = wid >> 1, wn = wid & 1;
    int lm = l & 15, lh = l >> 4;

    f32x4 acc[4][4];
    #pragma unroll
    for (int i = 0; i < 4; i++)
        #pragma unroll
        for (int j = 0; j < 4; j++) acc[i][j] = (f32x4){0.f,0.f,0.f,0.f};

    for (int kt = 0; kt < 32; ++kt) {
        __syncthreads();
        #pragma unroll
        for (int c = t; c < 512; c += 256) {
            int q = c >> 7, r = c & 127;
            int gm = m0 + r;                    // m' = t*64 + b
            int tt = gm >> 6, bb = gm & 63;
            size_t idx = (size_t)tt*65536 + (size_t)(bb>>4)*16384
                       + (size_t)(kt*4 + q)*128 + (size_t)(bb&15)*8;
            *reinterpret_cast<float4*>(&As[r][q*8]) =
                *reinterpret_cast<const float4*>(Hs + idx);
        }
        #pragma unroll
        for (int c = t; c < 512; c += 256) {
            int row = c >> 2, q = c & 3;
            *reinterpret_cast<float4*>(&Bs[row][q*8]) =
                *reinterpret_cast<const float4*>(Bm + (size_t)(n0+row)*1024 + kt*32 + q*8);
        }
        __syncthreads();

        f16x8 af[4], bf[4];
        #pragma unroll
        for (int i = 0; i < 4; i++)
            af[i] = *reinterpret_cast<const f16x8*>(&As[64*wm + 16*i + lm][8*lh]);
        #pragma unroll
        for (int j = 0; j < 4; j++)
            bf[j] = *reinterpret_cast<const f16x8*>(&Bs[64*wn + 16*j + lm][8*lh]);
        #pragma unroll
        for (int i = 0; i < 4; i++)
            #pragma unroll
            for (int j = 0; j < 4; j++)
                acc[i][j] = __builtin_amdgcn_mfma_f32_16x16x32_f16(af[i], bf[j], acc[i][j], 0, 0, 0);
    }

    int r0 = lh * 4;
    #pragma unroll
    for (int i = 0; i < 4; i++)
        #pragma unroll
        for (int j = 0; j < 4; j++) {
            int gmb = m0 + 64*wm + 16*i + r0;
            int gn  = n0 + 64*wn + 16*j + lm;
            #pragma unroll
            for (int r = 0; r < 4; r++) {
                int gm = gmb + r;               // m' = t*64 + b
                int bb = gm & 63, tt = gm >> 6;
                size_t o = ((size_t)bb*512 + tt)*1024 + gn;
                Out[o] += acc[i][j][r];
            }
        }
}

// ---------- workspace layout (bytes) ----------
// [0, 4M)        Wx f16 [2048][1024]
// [4M, 8M)       Wr f16 [2048][1024]   (rows 0..1023 = Wrh, 1024..2047 = Wro)
// [8M, 72M)      Xh f16 packed [512][4][128][16][8]
// [72M, 136M)    Hs f16 packed [512][4][128][16][8]
// [136M, +8K)    flags u32[2048]

extern "C" void kernel_launch(void* const* d_in, const int* in_sizes, int n_in,
                              void* d_out, int out_size, void* d_ws, size_t ws_size,
                              hipStream_t stream) {
    const float* X  = (const float*)d_in[0];
    const float* H0 = (const float*)d_in[1];
    const float* Wh = (const float*)d_in[2];
    const float* bh = (const float*)d_in[3];
    const float* Wo = (const float*)d_in[4];
    const float* bo = (const float*)d_in[5];
    float* Out = (float*)d_out;

    char* ws = (char*)d_ws;
    f16* Wx = (f16*)(ws);
    f16* Wr = (f16*)(ws + (size_t)4*1024*1024);
    f16* Xh = (f16*)(ws + (size_t)8*1024*1024);
    f16* Hs = (f16*)(ws + (size_t)8*1024*1024 + (size_t)M_TOT*1024*2);
    unsigned int* flags = (unsigned int*)(ws + (size_t)8*1024*1024 + (size_t)2*M_TOT*1024*2);

    hipLaunchKernelGGL(k_prep_w, dim3(2048), dim3(256), 0, stream, Wh, Wo, Wx, Wr);
    hipLaunchKernelGGL(k_init_h, dim3(32), dim3(256), 0, stream, H0, Hs);
    hipLaunchKernelGGL(k_zero_flags, dim3(8), dim3(256), 0, stream, flags);
    hipLaunchKernelGGL(k_gemm1, dim3(256, 16), dim3(256), 0, stream, X, Wx, bh, bo, Xh, Out);

    void* args[] = { (void*)&Wr, (void*)&Xh, (void*)&Hs, (void*)&flags };
    hipLaunchCooperativeKernel((const void*)k_rnn3, dim3(NWG_RNN), dim3(256), args, 0, stream);

    f16* Wro = Wr + (size_t)1024*1024;
    hipLaunchKernelGGL(k_gemm2, dim3(256, 8), dim3(256), 0, stream, Hs, Wro, Out);
}

// Round 8
// 2122.945 us; speedup vs baseline: 7.9391x; 1.8886x over previous
//
#include <hip/hip_runtime.h>
#include <hip/hip_bf16.h>

// RNNLayer: B=64, T=512, D_IN=D_H=D_OUT=1024.
// h_{t+1} = A h_t + u_t  (A = Wrh, u_t = x_t@Wxh^T + bh);  o_t = x_t@Wxo^T + h_t@Wro^T + bo
// Scan decomposition (sequential depth 511 -> 31 + 15):
//   tree:  v1=A u+u', v2=A2 v1+v1', v3=A4 v2+v2', v4=A8 v3+v3'  (plain GEMMs)
//   chain: h_{16(k+1)} = A16 h_{16k} + v4_k       (31 flag-sync steps, 64 WGs)
//   fill:  h_{16k+tau+1} = A h_{16k+tau} + u      (15 flag-sync steps, 256 WGs, nch=8)
// r7 failure root-cause: fill used 512 coop WGs (= exact occupancy limit) and the
// launch silently failed. r8: 256 WGs + return-code check + ordinary-launch fallback;
// amdgpu_waves_per_eu(1,1) to make the 128-VGPR weight slice truly register-resident.

typedef _Float16 f16;
typedef _Float16 f16x8 __attribute__((ext_vector_type(8)));
typedef _Float16 f16x4 __attribute__((ext_vector_type(4)));
typedef float f32x4 __attribute__((ext_vector_type(4)));
typedef int i32x4 __attribute__((ext_vector_type(4)));

#define T_LEN 512
#define BATCH 64
#define M_TOT (BATCH * T_LEN)   // 32768

// slab layout (per t): [bg 4][cblk 128][b 16][8] f16 = 65536 elems (128 KB)

// ---------- prep: stacked fp16 weights ----------
__global__ void k_prep_w(const float* __restrict__ Wh, const float* __restrict__ Wo,
                         f16* __restrict__ Wx, f16* __restrict__ Wr) {
    int n = blockIdx.x;              // 0..2047
    int t4 = threadIdx.x * 4;        // 0..1020
    const float* src = (n < 1024) ? (Wh + (size_t)n * 2048)
                                  : (Wo + (size_t)(n - 1024) * 2048);
    float4 a = *reinterpret_cast<const float4*>(src + t4);
    float4 b = *reinterpret_cast<const float4*>(src + 1024 + t4);
    f16x4 va, vb;
    va[0]=(f16)a.x; va[1]=(f16)a.y; va[2]=(f16)a.z; va[3]=(f16)a.w;
    vb[0]=(f16)b.x; vb[1]=(f16)b.y; vb[2]=(f16)b.z; vb[3]=(f16)b.w;
    *reinterpret_cast<f16x4*>(Wx + (size_t)n*1024 + t4) = va;
    *reinterpret_cast<f16x4*>(Wr + (size_t)n*1024 + t4) = vb;
}

// ---------- init: Hs[0] from H0 (packed layout) ----------
__global__ void k_init_h(const float* __restrict__ H0, f16* __restrict__ Hs) {
    int tid = blockIdx.x * 256 + threadIdx.x;   // 8192
    int b = tid >> 7, kb = tid & 127;
    float4 x0 = *reinterpret_cast<const float4*>(H0 + (size_t)b*1024 + kb*8);
    float4 x1 = *reinterpret_cast<const float4*>(H0 + (size_t)b*1024 + kb*8 + 4);
    f16x8 v;
    v[0]=(f16)x0.x; v[1]=(f16)x0.y; v[2]=(f16)x0.z; v[3]=(f16)x0.w;
    v[4]=(f16)x1.x; v[5]=(f16)x1.y; v[6]=(f16)x1.z; v[7]=(f16)x1.w;
    size_t idx = (size_t)(b >> 4)*16384 + (size_t)kb*128 + (size_t)(b & 15)*8;
    *reinterpret_cast<f16x8*>(Hs + idx) = v;
}

__global__ void k_zero_flags(unsigned int* __restrict__ flags) {
    flags[blockIdx.x * 256 + threadIdx.x] = 0;   // 2048 u32 (256 flags, 32B apart)
}

// ---------- phase 1: input projection GEMM (verified r6) ----------
__global__ __launch_bounds__(256) void k_gemm1(
    const float* __restrict__ Af, const f16* __restrict__ Bm,
    const float* __restrict__ bh, const float* __restrict__ bo,
    f16* __restrict__ Xh, float* __restrict__ Out)
{
    __shared__ f16 As[128][40];
    __shared__ f16 Bs[128][40];
    int m0 = blockIdx.x * 128;
    int n0 = blockIdx.y * 128;
    int t = threadIdx.x;
    int l = t & 63, wid = t >> 6;
    int wm = wid >> 1, wn = wid & 1;
    int lm = l & 15, lh = l >> 4;

    f32x4 acc[4][4];
    #pragma unroll
    for (int i = 0; i < 4; i++)
        #pragma unroll
        for (int j = 0; j < 4; j++) acc[i][j] = (f32x4){0.f,0.f,0.f,0.f};

    for (int kt = 0; kt < 32; ++kt) {
        int k0 = kt * 32;
        __syncthreads();
        #pragma unroll
        for (int c = t; c < 1024; c += 256) {
            int row = c >> 3, q = c & 7;
            float4 a = *reinterpret_cast<const float4*>(Af + (size_t)(m0+row)*1024 + k0 + q*4);
            f16x4 v; v[0]=(f16)a.x; v[1]=(f16)a.y; v[2]=(f16)a.z; v[3]=(f16)a.w;
            *reinterpret_cast<f16x4*>(&As[row][q*4]) = v;
        }
        #pragma unroll
        for (int c = t; c < 512; c += 256) {
            int row = c >> 2, q = c & 3;
            *reinterpret_cast<float4*>(&Bs[row][q*8]) =
                *reinterpret_cast<const float4*>(Bm + (size_t)(n0+row)*1024 + k0 + q*8);
        }
        __syncthreads();

        f16x8 af[4], bf[4];
        #pragma unroll
        for (int i = 0; i < 4; i++)
            af[i] = *reinterpret_cast<const f16x8*>(&As[64*wm + 16*i + lm][8*lh]);
        #pragma unroll
        for (int j = 0; j < 4; j++)
            bf[j] = *reinterpret_cast<const f16x8*>(&Bs[64*wn + 16*j + lm][8*lh]);
        #pragma unroll
        for (int i = 0; i < 4; i++)
            #pragma unroll
            for (int j = 0; j < 4; j++)
                acc[i][j] = __builtin_amdgcn_mfma_f32_16x16x32_f16(af[i], bf[j], acc[i][j], 0, 0, 0);
    }

    int r0 = lh * 4;
    bool isH = (n0 < 1024);
    #pragma unroll
    for (int i = 0; i < 4; i++)
        #pragma unroll
        for (int j = 0; j < 4; j++) {
            int gmb = m0 + 64*wm + 16*i + r0;
            int gn  = n0 + 64*wn + 16*j + lm;
            #pragma unroll
            for (int r = 0; r < 4; r++) {
                float v = acc[i][j][r];
                int gm = gmb + r;                 // m = b*512 + t
                if (isH) {
                    int tt = gm & 511, bb = gm >> 9;
                    size_t idx = (size_t)tt*65536 + (size_t)(bb>>4)*16384
                               + (size_t)(gn>>3)*128 + (size_t)(bb&15)*8 + (gn&7);
                    Xh[idx] = (f16)(v + bh[gn]);
                } else {
                    Out[(size_t)gm*1024 + (gn - 1024)] = v + bo[gn - 1024];
                }
            }
        }
}

// ---------- matrix squaring: Pout = P*P (B transposed in-LDS) ----------
__global__ __launch_bounds__(256) void k_sq(const f16* __restrict__ P, f16* __restrict__ Pout)
{
    __shared__ f16 As[128][40];
    __shared__ f16 Bs[128][40];
    int m0 = blockIdx.x * 128, n0 = blockIdx.y * 128;
    int t = threadIdx.x;
    int l = t & 63, wid = t >> 6;
    int wm = wid >> 1, wn = wid & 1;
    int lm = l & 15, lh = l >> 4;

    f32x4 acc[4][4];
    #pragma unroll
    for (int i = 0; i < 4; i++)
        #pragma unroll
        for (int j = 0; j < 4; j++) acc[i][j] = (f32x4){0.f,0.f,0.f,0.f};

    for (int kt = 0; kt < 32; ++kt) {
        __syncthreads();
        #pragma unroll
        for (int c = t; c < 512; c += 256) {       // A rows m, k-contig
            int row = c >> 2, q = c & 3;
            *reinterpret_cast<float4*>(&As[row][q*8]) =
                *reinterpret_cast<const float4*>(P + (size_t)(m0+row)*1024 + kt*32 + q*8);
        }
        #pragma unroll
        for (int c = t; c < 512; c += 256) {       // Bs[n][k] = P[k][n0+n]
            int r = c >> 4, q = c & 15;
            f16x8 v = *reinterpret_cast<const f16x8*>(P + (size_t)(kt*32 + r)*1024 + n0 + q*8);
            #pragma unroll
            for (int e = 0; e < 8; ++e) Bs[q*8+e][r] = v[e];
        }
        __syncthreads();

        f16x8 af[4], bf[4];
        #pragma unroll
        for (int i = 0; i < 4; i++)
            af[i] = *reinterpret_cast<const f16x8*>(&As[64*wm + 16*i + lm][8*lh]);
        #pragma unroll
        for (int j = 0; j < 4; j++)
            bf[j] = *reinterpret_cast<const f16x8*>(&Bs[64*wn + 16*j + lm][8*lh]);
        #pragma unroll
        for (int i = 0; i < 4; i++)
            #pragma unroll
            for (int j = 0; j < 4; j++)
                acc[i][j] = __builtin_amdgcn_mfma_f32_16x16x32_f16(af[i], bf[j], acc[i][j], 0, 0, 0);
    }

    int r0 = lh * 4;
    #pragma unroll
    for (int i = 0; i < 4; i++)
        #pragma unroll
        for (int j = 0; j < 4; j++) {
            int gmb = m0 + 64*wm + 16*i + r0;
            int gn  = n0 + 64*wn + 16*j + lm;
            #pragma unroll
            for (int r = 0; r < 4; r++)
                Pout[(size_t)(gmb+r)*1024 + gn] = (f16)acc[i][j][r];
        }
}

// ---------- v-level GEMM: Dst[k] = M * Src[f(2k)] + Src[f(2k+1)] ----------
__global__ __launch_bounds__(256) void k_vlevel(
    const f16* __restrict__ M, const f16* __restrict__ Src, f16* __restrict__ Dst,
    int srcOff, int srcStep, int dstOff, int dstStep)
{
    __shared__ f16 As[128][40];
    __shared__ f16 Bs[128][40];
    int m0 = blockIdx.x * 128;          // rows m = k*64 + b
    int n0 = blockIdx.y * 128;
    int t = threadIdx.x;
    int l = t & 63, wid = t >> 6;
    int wm = wid >> 1, wn = wid & 1;
    int lm = l & 15, lh = l >> 4;

    f32x4 acc[4][4];
    #pragma unroll
    for (int i = 0; i < 4; i++)
        #pragma unroll
        for (int j = 0; j < 4; j++) acc[i][j] = (f32x4){0.f,0.f,0.f,0.f};

    for (int kt = 0; kt < 32; ++kt) {
        __syncthreads();
        #pragma unroll
        for (int c = t; c < 512; c += 256) {   // A from packed src slabs
            int q = c >> 7, r = c & 127;
            int gm = m0 + r;
            int kd = gm >> 6, bb = gm & 63;
            size_t slab = (size_t)(srcOff + srcStep * (2*kd));
            *reinterpret_cast<float4*>(&As[r][q*8]) =
                *reinterpret_cast<const float4*>(Src + slab*65536 + (size_t)(bb>>4)*16384
                                                 + (size_t)(kt*4+q)*128 + (size_t)(bb&15)*8);
        }
        #pragma unroll
        for (int c = t; c < 512; c += 256) {   // B = M row-major
            int row = c >> 2, q = c & 3;
            *reinterpret_cast<float4*>(&Bs[row][q*8]) =
                *reinterpret_cast<const float4*>(M + (size_t)(n0+row)*1024 + kt*32 + q*8);
        }
        __syncthreads();

        f16x8 af[4], bf[4];
        #pragma unroll
        for (int i = 0; i < 4; i++)
            af[i] = *reinterpret_cast<const f16x8*>(&As[64*wm + 16*i + lm][8*lh]);
        #pragma unroll
        for (int j = 0; j < 4; j++)
            bf[j] = *reinterpret_cast<const f16x8*>(&Bs[64*wn + 16*j + lm][8*lh]);
        #pragma unroll
        for (int i = 0; i < 4; i++)
            #pragma unroll
            for (int j = 0; j < 4; j++)
                acc[i][j] = __builtin_amdgcn_mfma_f32_16x16x32_f16(af[i], bf[j], acc[i][j], 0, 0, 0);
    }

    int r0 = lh * 4;
    #pragma unroll
    for (int i = 0; i < 4; i++)
        #pragma unroll
        for (int j = 0; j < 4; j++) {
            int gmb = m0 + 64*wm + 16*i + r0;
            int gn  = n0 + 64*wn + 16*j + lm;
            #pragma unroll
            for (int r = 0; r < 4; r++) {
                int gm = gmb + r;
                int kd = gm >> 6, bb = gm & 63;
                size_t pidx = (size_t)(bb>>4)*16384 + (size_t)(gn>>3)*128
                            + (size_t)(bb&15)*8 + (gn&7);
                size_t aslab = (size_t)(srcOff + srcStep * (2*kd + 1));
                float add = (float)Src[aslab*65536 + pidx];
                size_t dslab = (size_t)(dstOff + dstStep * kd);
                Dst[dslab*65536 + pidx] = (f16)(acc[i][j][r] + add);
            }
        }
}

// ---------- flag-sync recurrence kernel ----------
// mode 1 (CHAIN): 64 WGs (p=0, nch=1). step t: Hs[16t] -> Hs[16t+16], u = Hs[16t+8] (v4).
// mode 2 (FILL): 256 WGs (4 p-groups x 8 chunks). step t: Hs[c*16+t] -> +1, u = Xh[c*16+t].
// WG: p = wg>>6, bg = (wg>>4)&3, cg = wg&15; poll set = 16 WGs (p,bg,*).
// waves_per_eu(1,1): 512-VGPR budget -> bw[32] (128 VGPR) truly resident (r6/r7 spilled).
__global__ void __launch_bounds__(256) __attribute__((amdgpu_waves_per_eu(1, 1)))
k_chain(
    const f16* __restrict__ W,        // [1024][1024] row-major (A or A16)
    const f16* __restrict__ U,        // u base (slab-packed)
    f16* __restrict__ Hs,
    unsigned int* __restrict__ flags,
    int nstep, int mode, int nch)
{
    int wg = blockIdx.x;
    int p  = wg >> 6;
    int bg = (wg >> 4) & 3;
    int cg = wg & 15;
    int w  = threadIdx.x >> 6;
    int l  = threadIdx.x & 63;
    int lm = l & 15, lh = l >> 4;
    int ccol = cg * 64 + w * 16 + lm;

    __shared__ f16 hbuf[16384];
    __shared__ float lt[4][16][17];

    f16x8 bw[32];
    #pragma unroll
    for (int kt = 0; kt < 32; ++kt)
        bw[kt] = *reinterpret_cast<const f16x8*>(W + (size_t)ccol * 1024 + kt*32 + lh*8);
    #pragma unroll
    for (int kt = 0; kt < 32; ++kt)
        asm volatile("" : "+v"(bw[kt]));

    const int flagBase = (p*4 + bg) * 16;
    int b_ep = l & 15, cb_ep = l >> 4;

    for (int t = 0; t < nstep; ++t) {
        if (t > 0) {
            if (threadIdx.x < 16) {
                unsigned int tgt = (unsigned int)t;
                const unsigned int* fp = &flags[(flagBase + (int)threadIdx.x) * 8];
                while (__hip_atomic_load(fp, __ATOMIC_RELAXED, __HIP_MEMORY_SCOPE_AGENT) < tgt)
                    __builtin_amdgcn_s_sleep(1);
            }
            __syncthreads();
            asm volatile("" ::: "memory");
        }

        for (int i = 0; i < nch; ++i) {
            int c = p * nch + i;
            size_t rSlab, wSlab, uSlab;
            if (mode == 1) { rSlab = (size_t)(16*t); wSlab = rSlab + 16; uSlab = rSlab + 8; }
            else           { rSlab = (size_t)(c*16 + t); wSlab = rSlab + 1; uSlab = rSlab; }

            if (i > 0) __syncthreads();   // hbuf reuse across chunks

            // u prefetch (source written by an earlier kernel / earlier-synced step)
            f16x8 xv;
            int cblk = cg*8 + w*2 + cb_ep;
            if (l < 32)
                xv = *reinterpret_cast<const f16x8*>(
                    U + uSlab*65536 + (size_t)bg*16384 + (size_t)cblk*128 + b_ep*8);

            // stage h slab (bg quarter, 32 KB) into LDS
            {
                const char* gsrc = (const char*)Hs + (rSlab*65536 + (size_t)bg*16384)*2
                                 + (size_t)w*8192 + (size_t)l*16;
                char* ldst = (char*)hbuf + (size_t)w*8192;
                #pragma unroll
                for (int q = 0; q < 8; ++q)
                    __builtin_amdgcn_global_load_lds(
                        (const __attribute__((address_space(1))) void*)(gsrc + q*1024),
                        (__attribute__((address_space(3))) void*)(ldst + q*1024),
                        16, 0, 0);
            }
            asm volatile("s_waitcnt vmcnt(0)" ::: "memory");
            __syncthreads();

            f32x4 a0 = (f32x4){0.f,0.f,0.f,0.f};
            f32x4 a1 = (f32x4){0.f,0.f,0.f,0.f};
            #pragma unroll 8
            for (int kt = 0; kt < 32; ++kt) {
                f16x8 af = *reinterpret_cast<const f16x8*>(&hbuf[(size_t)(kt*4 + lh)*128 + lm*8]);
                if (kt & 1) a1 = __builtin_amdgcn_mfma_f32_16x16x32_f16(af, bw[kt], a1, 0, 0, 0);
                else        a0 = __builtin_amdgcn_mfma_f32_16x16x32_f16(af, bw[kt], a0, 0, 0, 0);
            }
            f32x4 acc = a0 + a1;

            #pragma unroll
            for (int r = 0; r < 4; ++r)
                lt[w][lh*4 + r][lm] = acc[r];
            // wave-private RAW through LDS (compiler inserts lgkmcnt)

            if (l < 32) {
                f16x8 hv;
                #pragma unroll
                for (int e = 0; e < 8; ++e)
                    hv[e] = (f16)(lt[w][b_ep][cb_ep*8 + e] + (float)xv[e]);
                f16* dst = Hs + wSlab*65536 + (size_t)bg*16384 + (size_t)cblk*128 + b_ep*8;
                i32x4 iv = __builtin_bit_cast(i32x4, hv);
                asm volatile("global_store_dwordx4 %0, %1, off sc0 sc1"
                             :: "v"(dst), "v"(iv) : "memory");
            }
        }

        asm volatile("s_waitcnt vmcnt(0)" ::: "memory");
        __syncthreads();
        if (threadIdx.x == 0) {
            __builtin_amdgcn_fence(__ATOMIC_RELEASE, "agent");
            __hip_atomic_store(&flags[wg*8], (unsigned int)(t+1),
                               __ATOMIC_RELAXED, __HIP_MEMORY_SCOPE_AGENT);
        }
    }
}

// ---------- phase 3: output GEMM  Out += Hs @ Wro^T (verified r6) ----------
__global__ __launch_bounds__(256) void k_gemm2(
    const f16* __restrict__ Hs, const f16* __restrict__ Bm, float* __restrict__ Out)
{
    __shared__ f16 As[128][40];
    __shared__ f16 Bs[128][40];
    int m0 = blockIdx.x * 128;          // m' = t*64 + b
    int n0 = blockIdx.y * 128;
    int t = threadIdx.x;
    int l = t & 63, wid = t >> 6;
    int wm = wid >> 1, wn = wid & 1;
    int lm = l & 15, lh = l >> 4;

    f32x4 acc[4][4];
    #pragma unroll
    for (int i = 0; i < 4; i++)
        #pragma unroll
        for (int j = 0; j < 4; j++) acc[i][j] = (f32x4){0.f,0.f,0.f,0.f};

    for (int kt = 0; kt < 32; ++kt) {
        __syncthreads();
        #pragma unroll
        for (int c = t; c < 512; c += 256) {
            int q = c >> 7, r = c & 127;
            int gm = m0 + r;
            int tt = gm >> 6, bb = gm & 63;
            size_t idx = (size_t)tt*65536 + (size_t)(bb>>4)*16384
                       + (size_t)(kt*4 + q)*128 + (size_t)(bb&15)*8;
            *reinterpret_cast<float4*>(&As[r][q*8]) =
                *reinterpret_cast<const float4*>(Hs + idx);
        }
        #pragma unroll
        for (int c = t; c < 512; c += 256) {
            int row = c >> 2, q = c & 3;
            *reinterpret_cast<float4*>(&Bs[row][q*8]) =
                *reinterpret_cast<const float4*>(Bm + (size_t)(n0+row)*1024 + kt*32 + q*8);
        }
        __syncthreads();

        f16x8 af[4], bf[4];
        #pragma unroll
        for (int i = 0; i < 4; i++)
            af[i] = *reinterpret_cast<const f16x8*>(&As[64*wm + 16*i + lm][8*lh]);
        #pragma unroll
        for (int j = 0; j < 4; j++)
            bf[j] = *reinterpret_cast<const f16x8*>(&Bs[64*wn + 16*j + lm][8*lh]);
        #pragma unroll
        for (int i = 0; i < 4; i++)
            #pragma unroll
            for (int j = 0; j < 4; j++)
                acc[i][j] = __builtin_amdgcn_mfma_f32_16x16x32_f16(af[i], bf[j], acc[i][j], 0, 0, 0);
    }

    int r0 = lh * 4;
    #pragma unroll
    for (int i = 0; i < 4; i++)
        #pragma unroll
        for (int j = 0; j < 4; j++) {
            int gmb = m0 + 64*wm + 16*i + r0;
            int gn  = n0 + 64*wn + 16*j + lm;
            #pragma unroll
            for (int r = 0; r < 4; r++) {
                int gm = gmb + r;               // m' = t*64 + b
                int bb = gm & 63, tt = gm >> 6;
                size_t o = ((size_t)bb*512 + tt)*1024 + gn;
                Out[o] += acc[i][j][r];
            }
        }
}

// ---------- workspace layout (bytes) — 136.07 MB total ----------
// [0, 4M)      Wx (gemm1); afterwards Pa @0, Pb @2M (A-power ping-pong)
// [4M, 8M)     Wr  (rows 0..1023 = A = Wrh, rows 1024..2047 = Wro)
// [8M, 72M)    Xh  [512 slabs]
// [72M, 136M)  Hs  [512 slabs]; V1 -> slabs 1..256, V2 -> odd 257.., V3 -> 2+4m,
//              V4 -> 16c+8 (all dead before their slabs' final h is written)
// [136M, +8K)  flags u32[2048] (256 flags, 32B stride — proven region size)

extern "C" void kernel_launch(void* const* d_in, const int* in_sizes, int n_in,
                              void* d_out, int out_size, void* d_ws, size_t ws_size,
                              hipStream_t stream) {
    const float* X  = (const float*)d_in[0];
    const float* H0 = (const float*)d_in[1];
    const float* Wh = (const float*)d_in[2];
    const float* bh = (const float*)d_in[3];
    const float* Wo = (const float*)d_in[4];
    const float* bo = (const float*)d_in[5];
    float* Out = (float*)d_out;

    char* ws = (char*)d_ws;
    f16* Wx = (f16*)(ws);
    f16* Pa = (f16*)(ws);                               // aliases Wx (dead after gemm1)
    f16* Pb = (f16*)(ws + (size_t)2*1024*1024);
    f16* Wr = (f16*)(ws + (size_t)4*1024*1024);
    f16* Xh = (f16*)(ws + (size_t)8*1024*1024);
    f16* Hs = (f16*)(ws + (size_t)8*1024*1024 + (size_t)M_TOT*1024*2);
    unsigned int* flags = (unsigned int*)(ws + (size_t)8*1024*1024 + (size_t)2*M_TOT*1024*2);

    hipLaunchKernelGGL(k_prep_w, dim3(2048), dim3(256), 0, stream, Wh, Wo, Wx, Wr);
    hipLaunchKernelGGL(k_init_h, dim3(32), dim3(256), 0, stream, H0, Hs);
    hipLaunchKernelGGL(k_gemm1, dim3(256, 16), dim3(256), 0, stream, X, Wx, bh, bo, Xh, Out);

    // A-power / v-level interleave (each value consumed before overwrite)
    hipLaunchKernelGGL(k_sq, dim3(8,8), dim3(256), 0, stream, Wr, Pa);                   // Pa = A2
    hipLaunchKernelGGL(k_vlevel, dim3(128,8), dim3(256), 0, stream, Wr, Xh, Hs, 0,1, 1,1);     // V1
    hipLaunchKernelGGL(k_vlevel, dim3(64,8),  dim3(256), 0, stream, Pa, Hs, Hs, 1,1, 257,2);   // V2
    hipLaunchKernelGGL(k_sq, dim3(8,8), dim3(256), 0, stream, Pa, Pb);                   // Pb = A4
    hipLaunchKernelGGL(k_vlevel, dim3(32,8),  dim3(256), 0, stream, Pb, Hs, Hs, 257,2, 2,4);   // V3
    hipLaunchKernelGGL(k_sq, dim3(8,8), dim3(256), 0, stream, Pb, Pa);                   // Pa = A8
    hipLaunchKernelGGL(k_vlevel, dim3(16,8),  dim3(256), 0, stream, Pa, Hs, Hs, 2,4, 8,16);    // V4
    hipLaunchKernelGGL(k_sq, dim3(8,8), dim3(256), 0, stream, Pa, Pb);                   // Pb = A16

    // chain: h_{16(t+1)} = A16 h_{16t} + v4_t   (31 steps, 64 WGs)
    hipLaunchKernelGGL(k_zero_flags, dim3(8), dim3(256), 0, stream, flags);
    {
        int nstep = 31, mode = 1, nch = 1;
        void* args[] = { (void*)&Pb, (void*)&Hs, (void*)&Hs, (void*)&flags,
                         (void*)&nstep, (void*)&mode, (void*)&nch };
        if (hipLaunchCooperativeKernel((const void*)k_chain, dim3(64), dim3(256),
                                       args, 0, stream) != hipSuccess) {
            // fallback: 64 WGs <= worst-case capacity -> co-resident anyway
            hipLaunchKernelGGL(k_chain, dim3(64), dim3(256), 0, stream,
                               Pb, Hs, Hs, flags, 31, 1, 1);
        }
    }

    // fill: h_{c*16+t+1} = A h_{c*16+t} + u   (15 steps, 32 chunks, 256 WGs x nch=8)
    hipLaunchKernelGGL(k_zero_flags, dim3(8), dim3(256), 0, stream, flags);
    {
        int nstep = 15, mode = 2, nch = 8;
        void* args[] = { (void*)&Wr, (void*)&Xh, (void*)&Hs, (void*)&flags,
                         (void*)&nstep, (void*)&mode, (void*)&nch };
        if (hipLaunchCooperativeKernel((const void*)k_chain, dim3(256), dim3(256),
                                       args, 0, stream) != hipSuccess) {
            // fallback: 256 WGs = 1/CU worst-case capacity -> co-resident anyway
            hipLaunchKernelGGL(k_chain, dim3(256), dim3(256), 0, stream,
                               Wr, Xh, Hs, flags, 15, 2, 8);
        }
    }

    f16* Wro = Wr + (size_t)1024*1024;
    hipLaunchKernelGGL(k_gemm2, dim3(256, 8), dim3(256), 0, stream, Hs, Wro, Out);
}

// Round 9
// 1493.337 us; speedup vs baseline: 11.2864x; 1.4216x over previous
//
#include <hip/hip_runtime.h>
#include <hip/hip_bf16.h>

// RNNLayer: B=64, T=512, D_IN=D_H=D_OUT=1024.
// h_{t+1} = A h_t + u_t  (A = Wrh, u_t = x_t@Wxh^T + bh);  o_t = x_t@Wxo^T + h_t@Wro^T + bo
// Scan decomposition (sequential depth 511 -> 31 + 15):
//   tree:  v1=A u+u', v2=A2 v1+v1', v3=A4 v2+v2', v4=A8 v3+v3'  (plain GEMMs)
//   chain: h_{16(k+1)} = A16 h_{16k} + v4_k       (31 flag-sync steps, 64 WGs)
//   fill:  h_{16k+tau+1} = A h_{16k+tau} + u      (15 flag-sync steps, 256 WGs, nch=8)
// r8 -> r9: (1) FULL unroll of the kt loop — partial unroll left bw[kt]
// runtime-indexed -> scratch (rule #20): VGPR=132, FETCH=1.8GB of scratch/slab
// re-reads. (2) XCD-aware WG renumbering so each flag-group's 16 WGs share one
// XCD L2 (kills the 16x slab-fetch amplification). Flags keyed by LOGICAL id,
// protocol unchanged -> correctness placement-independent.

typedef _Float16 f16;
typedef _Float16 f16x8 __attribute__((ext_vector_type(8)));
typedef _Float16 f16x4 __attribute__((ext_vector_type(4)));
typedef float f32x4 __attribute__((ext_vector_type(4)));
typedef int i32x4 __attribute__((ext_vector_type(4)));

#define T_LEN 512
#define BATCH 64
#define M_TOT (BATCH * T_LEN)   // 32768

// slab layout (per t): [bg 4][cblk 128][b 16][8] f16 = 65536 elems (128 KB)

// ---------- prep: stacked fp16 weights ----------
__global__ void k_prep_w(const float* __restrict__ Wh, const float* __restrict__ Wo,
                         f16* __restrict__ Wx, f16* __restrict__ Wr) {
    int n = blockIdx.x;              // 0..2047
    int t4 = threadIdx.x * 4;        // 0..1020
    const float* src = (n < 1024) ? (Wh + (size_t)n * 2048)
                                  : (Wo + (size_t)(n - 1024) * 2048);
    float4 a = *reinterpret_cast<const float4*>(src + t4);
    float4 b = *reinterpret_cast<const float4*>(src + 1024 + t4);
    f16x4 va, vb;
    va[0]=(f16)a.x; va[1]=(f16)a.y; va[2]=(f16)a.z; va[3]=(f16)a.w;
    vb[0]=(f16)b.x; vb[1]=(f16)b.y; vb[2]=(f16)b.z; vb[3]=(f16)b.w;
    *reinterpret_cast<f16x4*>(Wx + (size_t)n*1024 + t4) = va;
    *reinterpret_cast<f16x4*>(Wr + (size_t)n*1024 + t4) = vb;
}

// ---------- init: Hs[0] from H0 (packed layout) ----------
__global__ void k_init_h(const float* __restrict__ H0, f16* __restrict__ Hs) {
    int tid = blockIdx.x * 256 + threadIdx.x;   // 8192
    int b = tid >> 7, kb = tid & 127;
    float4 x0 = *reinterpret_cast<const float4*>(H0 + (size_t)b*1024 + kb*8);
    float4 x1 = *reinterpret_cast<const float4*>(H0 + (size_t)b*1024 + kb*8 + 4);
    f16x8 v;
    v[0]=(f16)x0.x; v[1]=(f16)x0.y; v[2]=(f16)x0.z; v[3]=(f16)x0.w;
    v[4]=(f16)x1.x; v[5]=(f16)x1.y; v[6]=(f16)x1.z; v[7]=(f16)x1.w;
    size_t idx = (size_t)(b >> 4)*16384 + (size_t)kb*128 + (size_t)(b & 15)*8;
    *reinterpret_cast<f16x8*>(Hs + idx) = v;
}

__global__ void k_zero_flags(unsigned int* __restrict__ flags) {
    flags[blockIdx.x * 256 + threadIdx.x] = 0;   // 2048 u32 (256 logical flags, 32B apart)
}

// ---------- phase 1: input projection GEMM (verified r6) ----------
__global__ __launch_bounds__(256) void k_gemm1(
    const float* __restrict__ Af, const f16* __restrict__ Bm,
    const float* __restrict__ bh, const float* __restrict__ bo,
    f16* __restrict__ Xh, float* __restrict__ Out)
{
    __shared__ f16 As[128][40];
    __shared__ f16 Bs[128][40];
    int m0 = blockIdx.x * 128;
    int n0 = blockIdx.y * 128;
    int t = threadIdx.x;
    int l = t & 63, wid = t >> 6;
    int wm = wid >> 1, wn = wid & 1;
    int lm = l & 15, lh = l >> 4;

    f32x4 acc[4][4];
    #pragma unroll
    for (int i = 0; i < 4; i++)
        #pragma unroll
        for (int j = 0; j < 4; j++) acc[i][j] = (f32x4){0.f,0.f,0.f,0.f};

    for (int kt = 0; kt < 32; ++kt) {
        int k0 = kt * 32;
        __syncthreads();
        #pragma unroll
        for (int c = t; c < 1024; c += 256) {
            int row = c >> 3, q = c & 7;
            float4 a = *reinterpret_cast<const float4*>(Af + (size_t)(m0+row)*1024 + k0 + q*4);
            f16x4 v; v[0]=(f16)a.x; v[1]=(f16)a.y; v[2]=(f16)a.z; v[3]=(f16)a.w;
            *reinterpret_cast<f16x4*>(&As[row][q*4]) = v;
        }
        #pragma unroll
        for (int c = t; c < 512; c += 256) {
            int row = c >> 2, q = c & 3;
            *reinterpret_cast<float4*>(&Bs[row][q*8]) =
                *reinterpret_cast<const float4*>(Bm + (size_t)(n0+row)*1024 + k0 + q*8);
        }
        __syncthreads();

        f16x8 af[4], bf[4];
        #pragma unroll
        for (int i = 0; i < 4; i++)
            af[i] = *reinterpret_cast<const f16x8*>(&As[64*wm + 16*i + lm][8*lh]);
        #pragma unroll
        for (int j = 0; j < 4; j++)
            bf[j] = *reinterpret_cast<const f16x8*>(&Bs[64*wn + 16*j + lm][8*lh]);
        #pragma unroll
        for (int i = 0; i < 4; i++)
            #pragma unroll
            for (int j = 0; j < 4; j++)
                acc[i][j] = __builtin_amdgcn_mfma_f32_16x16x32_f16(af[i], bf[j], acc[i][j], 0, 0, 0);
    }

    int r0 = lh * 4;
    bool isH = (n0 < 1024);
    #pragma unroll
    for (int i = 0; i < 4; i++)
        #pragma unroll
        for (int j = 0; j < 4; j++) {
            int gmb = m0 + 64*wm + 16*i + r0;
            int gn  = n0 + 64*wn + 16*j + lm;
            #pragma unroll
            for (int r = 0; r < 4; r++) {
                float v = acc[i][j][r];
                int gm = gmb + r;                 // m = b*512 + t
                if (isH) {
                    int tt = gm & 511, bb = gm >> 9;
                    size_t idx = (size_t)tt*65536 + (size_t)(bb>>4)*16384
                               + (size_t)(gn>>3)*128 + (size_t)(bb&15)*8 + (gn&7);
                    Xh[idx] = (f16)(v + bh[gn]);
                } else {
                    Out[(size_t)gm*1024 + (gn - 1024)] = v + bo[gn - 1024];
                }
            }
        }
}

// ---------- matrix squaring: Pout = P*P (B transposed in-LDS) ----------
__global__ __launch_bounds__(256) void k_sq(const f16* __restrict__ P, f16* __restrict__ Pout)
{
    __shared__ f16 As[128][40];
    __shared__ f16 Bs[128][40];
    int m0 = blockIdx.x * 128, n0 = blockIdx.y * 128;
    int t = threadIdx.x;
    int l = t & 63, wid = t >> 6;
    int wm = wid >> 1, wn = wid & 1;
    int lm = l & 15, lh = l >> 4;

    f32x4 acc[4][4];
    #pragma unroll
    for (int i = 0; i < 4; i++)
        #pragma unroll
        for (int j = 0; j < 4; j++) acc[i][j] = (f32x4){0.f,0.f,0.f,0.f};

    for (int kt = 0; kt < 32; ++kt) {
        __syncthreads();
        #pragma unroll
        for (int c = t; c < 512; c += 256) {       // A rows m, k-contig
            int row = c >> 2, q = c & 3;
            *reinterpret_cast<float4*>(&As[row][q*8]) =
                *reinterpret_cast<const float4*>(P + (size_t)(m0+row)*1024 + kt*32 + q*8);
        }
        #pragma unroll
        for (int c = t; c < 512; c += 256) {       // Bs[n][k] = P[k][n0+n]
            int r = c >> 4, q = c & 15;
            f16x8 v = *reinterpret_cast<const f16x8*>(P + (size_t)(kt*32 + r)*1024 + n0 + q*8);
            #pragma unroll
            for (int e = 0; e < 8; ++e) Bs[q*8+e][r] = v[e];
        }
        __syncthreads();

        f16x8 af[4], bf[4];
        #pragma unroll
        for (int i = 0; i < 4; i++)
            af[i] = *reinterpret_cast<const f16x8*>(&As[64*wm + 16*i + lm][8*lh]);
        #pragma unroll
        for (int j = 0; j < 4; j++)
            bf[j] = *reinterpret_cast<const f16x8*>(&Bs[64*wn + 16*j + lm][8*lh]);
        #pragma unroll
        for (int i = 0; i < 4; i++)
            #pragma unroll
            for (int j = 0; j < 4; j++)
                acc[i][j] = __builtin_amdgcn_mfma_f32_16x16x32_f16(af[i], bf[j], acc[i][j], 0, 0, 0);
    }

    int r0 = lh * 4;
    #pragma unroll
    for (int i = 0; i < 4; i++)
        #pragma unroll
        for (int j = 0; j < 4; j++) {
            int gmb = m0 + 64*wm + 16*i + r0;
            int gn  = n0 + 64*wn + 16*j + lm;
            #pragma unroll
            for (int r = 0; r < 4; r++)
                Pout[(size_t)(gmb+r)*1024 + gn] = (f16)acc[i][j][r];
        }
}

// ---------- v-level GEMM: Dst[k] = M * Src[f(2k)] + Src[f(2k+1)] ----------
__global__ __launch_bounds__(256) void k_vlevel(
    const f16* __restrict__ M, const f16* __restrict__ Src, f16* __restrict__ Dst,
    int srcOff, int srcStep, int dstOff, int dstStep)
{
    __shared__ f16 As[128][40];
    __shared__ f16 Bs[128][40];
    int m0 = blockIdx.x * 128;          // rows m = k*64 + b
    int n0 = blockIdx.y * 128;
    int t = threadIdx.x;
    int l = t & 63, wid = t >> 6;
    int wm = wid >> 1, wn = wid & 1;
    int lm = l & 15, lh = l >> 4;

    f32x4 acc[4][4];
    #pragma unroll
    for (int i = 0; i < 4; i++)
        #pragma unroll
        for (int j = 0; j < 4; j++) acc[i][j] = (f32x4){0.f,0.f,0.f,0.f};

    for (int kt = 0; kt < 32; ++kt) {
        __syncthreads();
        #pragma unroll
        for (int c = t; c < 512; c += 256) {   // A from packed src slabs
            int q = c >> 7, r = c & 127;
            int gm = m0 + r;
            int kd = gm >> 6, bb = gm & 63;
            size_t slab = (size_t)(srcOff + srcStep * (2*kd));
            *reinterpret_cast<float4*>(&As[r][q*8]) =
                *reinterpret_cast<const float4*>(Src + slab*65536 + (size_t)(bb>>4)*16384
                                                 + (size_t)(kt*4+q)*128 + (size_t)(bb&15)*8);
        }
        #pragma unroll
        for (int c = t; c < 512; c += 256) {   // B = M row-major
            int row = c >> 2, q = c & 3;
            *reinterpret_cast<float4*>(&Bs[row][q*8]) =
                *reinterpret_cast<const float4*>(M + (size_t)(n0+row)*1024 + kt*32 + q*8);
        }
        __syncthreads();

        f16x8 af[4], bf[4];
        #pragma unroll
        for (int i = 0; i < 4; i++)
            af[i] = *reinterpret_cast<const f16x8*>(&As[64*wm + 16*i + lm][8*lh]);
        #pragma unroll
        for (int j = 0; j < 4; j++)
            bf[j] = *reinterpret_cast<const f16x8*>(&Bs[64*wn + 16*j + lm][8*lh]);
        #pragma unroll
        for (int i = 0; i < 4; i++)
            #pragma unroll
            for (int j = 0; j < 4; j++)
                acc[i][j] = __builtin_amdgcn_mfma_f32_16x16x32_f16(af[i], bf[j], acc[i][j], 0, 0, 0);
    }

    int r0 = lh * 4;
    #pragma unroll
    for (int i = 0; i < 4; i++)
        #pragma unroll
        for (int j = 0; j < 4; j++) {
            int gmb = m0 + 64*wm + 16*i + r0;
            int gn  = n0 + 64*wn + 16*j + lm;
            #pragma unroll
            for (int r = 0; r < 4; r++) {
                int gm = gmb + r;
                int kd = gm >> 6, bb = gm & 63;
                size_t pidx = (size_t)(bb>>4)*16384 + (size_t)(gn>>3)*128
                            + (size_t)(bb&15)*8 + (gn&7);
                size_t aslab = (size_t)(srcOff + srcStep * (2*kd + 1));
                float add = (float)Src[aslab*65536 + pidx];
                size_t dslab = (size_t)(dstOff + dstStep * kd);
                Dst[dslab*65536 + pidx] = (f16)(acc[i][j][r] + add);
            }
        }
}

// ---------- flag-sync recurrence kernel ----------
// mode 1 (CHAIN): 64 WGs. step t: Hs[16t] -> Hs[16t+16], u = Hs[16t+8] (v4).
//   decode: r=wg&7, s=wg>>3: g=bg=r>>1, cg=((r&1)<<3)|s, p=0  (group on XCD pair)
// mode 2 (FILL): 256 WGs. step t: Hs[c*16+t] -> +1, u = Xh[c*16+t], c=p*8+i.
//   decode: r=wg&7, s=wg>>3: g=2r+(s>>4), cg=s&15, p=g>>2, bg=g&3 (group on one XCD)
// Flags keyed by LOGICAL id g*16+cg -> protocol placement-independent; the
// swizzle only restores L2 locality (slab quarter fetched once per XCD).
__global__ void __launch_bounds__(256) __attribute__((amdgpu_waves_per_eu(1, 1)))
k_chain(
    const f16* __restrict__ W,        // [1024][1024] row-major (A or A16)
    const f16* __restrict__ U,        // u base (slab-packed)
    f16* __restrict__ Hs,
    unsigned int* __restrict__ flags,
    int nstep, int mode, int nch)
{
    int wg = blockIdx.x;
    int r_ = wg & 7, s_ = wg >> 3;
    int g, cg, p, bg;
    if (mode == 1) { g = r_ >> 1; cg = ((r_ & 1) << 3) | s_; p = 0;       bg = g;     }
    else           { g = 2*r_ + (s_ >> 4); cg = s_ & 15;     p = g >> 2;  bg = g & 3; }
    int w  = threadIdx.x >> 6;
    int l  = threadIdx.x & 63;
    int lm = l & 15, lh = l >> 4;
    int ccol = cg * 64 + w * 16 + lm;

    __shared__ f16 hbuf[16384];
    __shared__ float lt[4][16][17];

    // register-resident recurrent weights: 16 cols x K=1024 = 128 VGPRs/lane.
    // All bw indices below are compile-time (FULL unroll) — rule #20.
    f16x8 bw[32];
    #pragma unroll
    for (int kt = 0; kt < 32; ++kt)
        bw[kt] = *reinterpret_cast<const f16x8*>(W + (size_t)ccol * 1024 + kt*32 + lh*8);
    #pragma unroll
    for (int kt = 0; kt < 32; ++kt)
        asm volatile("" : "+v"(bw[kt]));

    const int flagBase = g * 16;
    int b_ep = l & 15, cb_ep = l >> 4;

    for (int t = 0; t < nstep; ++t) {
        if (t > 0) {
            if (threadIdx.x < 16) {
                unsigned int tgt = (unsigned int)t;
                const unsigned int* fp = &flags[(flagBase + (int)threadIdx.x) * 8];
                while (__hip_atomic_load(fp, __ATOMIC_RELAXED, __HIP_MEMORY_SCOPE_AGENT) < tgt)
                    __builtin_amdgcn_s_sleep(1);
            }
            __syncthreads();
            asm volatile("" ::: "memory");
        }

        for (int i = 0; i < nch; ++i) {
            int c = p * nch + i;
            size_t rSlab, wSlab, uSlab;
            if (mode == 1) { rSlab = (size_t)(16*t); wSlab = rSlab + 16; uSlab = rSlab + 8; }
            else           { rSlab = (size_t)(c*16 + t); wSlab = rSlab + 1; uSlab = rSlab; }

            if (i > 0) __syncthreads();   // hbuf reuse across chunks

            // u prefetch (source written by an earlier kernel / earlier-synced step)
            f16x8 xv;
            int cblk = cg*8 + w*2 + cb_ep;
            if (l < 32)
                xv = *reinterpret_cast<const f16x8*>(
                    U + uSlab*65536 + (size_t)bg*16384 + (size_t)cblk*128 + b_ep*8);

            // stage h slab (bg quarter, 32 KB) into LDS
            {
                const char* gsrc = (const char*)Hs + (rSlab*65536 + (size_t)bg*16384)*2
                                 + (size_t)w*8192 + (size_t)l*16;
                char* ldst = (char*)hbuf + (size_t)w*8192;
                #pragma unroll
                for (int q = 0; q < 8; ++q)
                    __builtin_amdgcn_global_load_lds(
                        (const __attribute__((address_space(1))) void*)(gsrc + q*1024),
                        (__attribute__((address_space(3))) void*)(ldst + q*1024),
                        16, 0, 0);
            }
            asm volatile("s_waitcnt vmcnt(0)" ::: "memory");
            __syncthreads();

            f32x4 a0 = (f32x4){0.f,0.f,0.f,0.f};
            f32x4 a1 = (f32x4){0.f,0.f,0.f,0.f};
            #pragma unroll
            for (int kt = 0; kt < 32; ++kt) {
                f16x8 af = *reinterpret_cast<const f16x8*>(&hbuf[(size_t)(kt*4 + lh)*128 + lm*8]);
                if (kt & 1) a1 = __builtin_amdgcn_mfma_f32_16x16x32_f16(af, bw[kt], a1, 0, 0, 0);
                else        a0 = __builtin_amdgcn_mfma_f32_16x16x32_f16(af, bw[kt], a0, 0, 0, 0);
            }
            f32x4 acc = a0 + a1;

            #pragma unroll
            for (int r = 0; r < 4; ++r)
                lt[w][lh*4 + r][lm] = acc[r];
            // wave-private RAW through LDS (compiler inserts lgkmcnt)

            if (l < 32) {
                f16x8 hv;
                #pragma unroll
                for (int e = 0; e < 8; ++e)
                    hv[e] = (f16)(lt[w][b_ep][cb_ep*8 + e] + (float)xv[e]);
                f16* dst = Hs + wSlab*65536 + (size_t)bg*16384 + (size_t)cblk*128 + b_ep*8;
                i32x4 iv = __builtin_bit_cast(i32x4, hv);
                asm volatile("global_store_dwordx4 %0, %1, off sc0 sc1"
                             :: "v"(dst), "v"(iv) : "memory");
            }
        }

        asm volatile("s_waitcnt vmcnt(0)" ::: "memory");
        __syncthreads();
        if (threadIdx.x == 0) {
            __builtin_amdgcn_fence(__ATOMIC_RELEASE, "agent");
            __hip_atomic_store(&flags[(flagBase + cg)*8], (unsigned int)(t+1),
                               __ATOMIC_RELAXED, __HIP_MEMORY_SCOPE_AGENT);
        }
    }
}

// ---------- phase 3: output GEMM  Out += Hs @ Wro^T (verified r6) ----------
__global__ __launch_bounds__(256) void k_gemm2(
    const f16* __restrict__ Hs, const f16* __restrict__ Bm, float* __restrict__ Out)
{
    __shared__ f16 As[128][40];
    __shared__ f16 Bs[128][40];
    int m0 = blockIdx.x * 128;          // m' = t*64 + b
    int n0 = blockIdx.y * 128;
    int t = threadIdx.x;
    int l = t & 63, wid = t >> 6;
    int wm = wid >> 1, wn = wid & 1;
    int lm = l & 15, lh = l >> 4;

    f32x4 acc[4][4];
    #pragma unroll
    for (int i = 0; i < 4; i++)
        #pragma unroll
        for (int j = 0; j < 4; j++) acc[i][j] = (f32x4){0.f,0.f,0.f,0.f};

    for (int kt = 0; kt < 32; ++kt) {
        __syncthreads();
        #pragma unroll
        for (int c = t; c < 512; c += 256) {
            int q = c >> 7, r = c & 127;
            int gm = m0 + r;
            int tt = gm >> 6, bb = gm & 63;
            size_t idx = (size_t)tt*65536 + (size_t)(bb>>4)*16384
                       + (size_t)(kt*4 + q)*128 + (size_t)(bb&15)*8;
            *reinterpret_cast<float4*>(&As[r][q*8]) =
                *reinterpret_cast<const float4*>(Hs + idx);
        }
        #pragma unroll
        for (int c = t; c < 512; c += 256) {
            int row = c >> 2, q = c & 3;
            *reinterpret_cast<float4*>(&Bs[row][q*8]) =
                *reinterpret_cast<const float4*>(Bm + (size_t)(n0+row)*1024 + kt*32 + q*8);
        }
        __syncthreads();

        f16x8 af[4], bf[4];
        #pragma unroll
        for (int i = 0; i < 4; i++)
            af[i] = *reinterpret_cast<const f16x8*>(&As[64*wm + 16*i + lm][8*lh]);
        #pragma unroll
        for (int j = 0; j < 4; j++)
            bf[j] = *reinterpret_cast<const f16x8*>(&Bs[64*wn + 16*j + lm][8*lh]);
        #pragma unroll
        for (int i = 0; i < 4; i++)
            #pragma unroll
            for (int j = 0; j < 4; j++)
                acc[i][j] = __builtin_amdgcn_mfma_f32_16x16x32_f16(af[i], bf[j], acc[i][j], 0, 0, 0);
    }

    int r0 = lh * 4;
    #pragma unroll
    for (int i = 0; i < 4; i++)
        #pragma unroll
        for (int j = 0; j < 4; j++) {
            int gmb = m0 + 64*wm + 16*i + r0;
            int gn  = n0 + 64*wn + 16*j + lm;
            #pragma unroll
            for (int r = 0; r < 4; r++) {
                int gm = gmb + r;               // m' = t*64 + b
                int bb = gm & 63, tt = gm >> 6;
                size_t o = ((size_t)bb*512 + tt)*1024 + gn;
                Out[o] += acc[i][j][r];
            }
        }
}

// ---------- workspace layout (bytes) — 136.07 MB total ----------
// [0, 4M)      Wx (gemm1); afterwards Pa @0, Pb @2M (A-power ping-pong)
// [4M, 8M)     Wr  (rows 0..1023 = A = Wrh, rows 1024..2047 = Wro)
// [8M, 72M)    Xh  [512 slabs]
// [72M, 136M)  Hs  [512 slabs]; V1 -> slabs 1..256, V2 -> odd 257.., V3 -> 2+4m,
//              V4 -> 16c+8 (all dead before their slabs' final h is written)
// [136M, +8K)  flags u32[2048] (256 logical flags, 32B stride)

extern "C" void kernel_launch(void* const* d_in, const int* in_sizes, int n_in,
                              void* d_out, int out_size, void* d_ws, size_t ws_size,
                              hipStream_t stream) {
    const float* X  = (const float*)d_in[0];
    const float* H0 = (const float*)d_in[1];
    const float* Wh = (const float*)d_in[2];
    const float* bh = (const float*)d_in[3];
    const float* Wo = (const float*)d_in[4];
    const float* bo = (const float*)d_in[5];
    float* Out = (float*)d_out;

    char* ws = (char*)d_ws;
    f16* Wx = (f16*)(ws);
    f16* Pa = (f16*)(ws);                               // aliases Wx (dead after gemm1)
    f16* Pb = (f16*)(ws + (size_t)2*1024*1024);
    f16* Wr = (f16*)(ws + (size_t)4*1024*1024);
    f16* Xh = (f16*)(ws + (size_t)8*1024*1024);
    f16* Hs = (f16*)(ws + (size_t)8*1024*1024 + (size_t)M_TOT*1024*2);
    unsigned int* flags = (unsigned int*)(ws + (size_t)8*1024*1024 + (size_t)2*M_TOT*1024*2);

    hipLaunchKernelGGL(k_prep_w, dim3(2048), dim3(256), 0, stream, Wh, Wo, Wx, Wr);
    hipLaunchKernelGGL(k_init_h, dim3(32), dim3(256), 0, stream, H0, Hs);
    hipLaunchKernelGGL(k_gemm1, dim3(256, 16), dim3(256), 0, stream, X, Wx, bh, bo, Xh, Out);

    // A-power / v-level interleave (each value consumed before overwrite)
    hipLaunchKernelGGL(k_sq, dim3(8,8), dim3(256), 0, stream, Wr, Pa);                   // Pa = A2
    hipLaunchKernelGGL(k_vlevel, dim3(128,8), dim3(256), 0, stream, Wr, Xh, Hs, 0,1, 1,1);     // V1
    hipLaunchKernelGGL(k_vlevel, dim3(64,8),  dim3(256), 0, stream, Pa, Hs, Hs, 1,1, 257,2);   // V2
    hipLaunchKernelGGL(k_sq, dim3(8,8), dim3(256), 0, stream, Pa, Pb);                   // Pb = A4
    hipLaunchKernelGGL(k_vlevel, dim3(32,8),  dim3(256), 0, stream, Pb, Hs, Hs, 257,2, 2,4);   // V3
    hipLaunchKernelGGL(k_sq, dim3(8,8), dim3(256), 0, stream, Pb, Pa);                   // Pa = A8
    hipLaunchKernelGGL(k_vlevel, dim3(16,8),  dim3(256), 0, stream, Pa, Hs, Hs, 2,4, 8,16);    // V4
    hipLaunchKernelGGL(k_sq, dim3(8,8), dim3(256), 0, stream, Pa, Pb);                   // Pb = A16

    // chain: h_{16(t+1)} = A16 h_{16t} + v4_t   (31 steps, 64 WGs)
    hipLaunchKernelGGL(k_zero_flags, dim3(8), dim3(256), 0, stream, flags);
    {
        int nstep = 31, mode = 1, nch = 1;
        void* args[] = { (void*)&Pb, (void*)&Hs, (void*)&Hs, (void*)&flags,
                         (void*)&nstep, (void*)&mode, (void*)&nch };
        if (hipLaunchCooperativeKernel((const void*)k_chain, dim3(64), dim3(256),
                                       args, 0, stream) != hipSuccess) {
            hipLaunchKernelGGL(k_chain, dim3(64), dim3(256), 0, stream,
                               Pb, Hs, Hs, flags, 31, 1, 1);
        }
    }

    // fill: h_{c*16+t+1} = A h_{c*16+t} + u   (15 steps, 32 chunks, 256 WGs x nch=8)
    hipLaunchKernelGGL(k_zero_flags, dim3(8), dim3(256), 0, stream, flags);
    {
        int nstep = 15, mode = 2, nch = 8;
        void* args[] = { (void*)&Wr, (void*)&Xh, (void*)&Hs, (void*)&flags,
                         (void*)&nstep, (void*)&mode, (void*)&nch };
        if (hipLaunchCooperativeKernel((const void*)k_chain, dim3(256), dim3(256),
                                       args, 0, stream) != hipSuccess) {
            hipLaunchKernelGGL(k_chain, dim3(256), dim3(256), 0, stream,
                               Wr, Xh, Hs, flags, 15, 2, 8);
        }
    }

    f16* Wro = Wr + (size_t)1024*1024;
    hipLaunchKernelGGL(k_gemm2, dim3(256, 8), dim3(256), 0, stream, Hs, Wro, Out);
}

// Round 10
// 1262.599 us; speedup vs baseline: 13.3489x; 1.1827x over previous
//
#include <hip/hip_runtime.h>
#include <hip/hip_bf16.h>

// RNNLayer: B=64, T=512, D_IN=D_H=D_OUT=1024.
// h_{t+1} = A h_t + u_t  (A = Wrh, u_t = x_t@Wxh^T + bh);  o_t = x_t@Wxo^T + h_t@Wro^T + bo
// Scan decomposition (sequential depth 511 -> 31 + 15):
//   tree:  v1=A u+u', v2=A2 v1+v1', v3=A4 v2+v2', v4=A8 v3+v3'  (plain GEMMs)
//   chain: h_{16(k+1)} = A16 h_{16k} + v4_k       (31 flag-sync steps, 64 WGs)
//   fill:  h_{16k+tau+1} = A h_{16k+tau} + u      (15 flag-sync steps, 256 WGs, nch=8)
// r9 -> r10: gemm1 rebuilt on the m97 structure — X pre-converted to f16 (Xf,
// aliased over the dead-until-after-gemm1 Hs region), A and B staged via
// global_load_lds width=16 into linear LDS. All other kernels byte-identical
// to the r9-verified versions.

typedef _Float16 f16;
typedef _Float16 f16x8 __attribute__((ext_vector_type(8)));
typedef _Float16 f16x4 __attribute__((ext_vector_type(4)));
typedef float f32x4 __attribute__((ext_vector_type(4)));
typedef int i32x4 __attribute__((ext_vector_type(4)));

#define T_LEN 512
#define BATCH 64
#define M_TOT (BATCH * T_LEN)   // 32768

// slab layout (per t): [bg 4][cblk 128][b 16][8] f16 = 65536 elems (128 KB)

// ---------- prep: stacked fp16 weights ----------
__global__ void k_prep_w(const float* __restrict__ Wh, const float* __restrict__ Wo,
                         f16* __restrict__ Wx, f16* __restrict__ Wr) {
    int n = blockIdx.x;              // 0..2047
    int t4 = threadIdx.x * 4;        // 0..1020
    const float* src = (n < 1024) ? (Wh + (size_t)n * 2048)
                                  : (Wo + (size_t)(n - 1024) * 2048);
    float4 a = *reinterpret_cast<const float4*>(src + t4);
    float4 b = *reinterpret_cast<const float4*>(src + 1024 + t4);
    f16x4 va, vb;
    va[0]=(f16)a.x; va[1]=(f16)a.y; va[2]=(f16)a.z; va[3]=(f16)a.w;
    vb[0]=(f16)b.x; vb[1]=(f16)b.y; vb[2]=(f16)b.z; vb[3]=(f16)b.w;
    *reinterpret_cast<f16x4*>(Wx + (size_t)n*1024 + t4) = va;
    *reinterpret_cast<f16x4*>(Wr + (size_t)n*1024 + t4) = vb;
}

// ---------- prep: X f32 -> Xf f16 row-major [32768][1024] ----------
__global__ void k_prep_x(const float* __restrict__ X, f16* __restrict__ Xf) {
    size_t i = ((size_t)blockIdx.x * 256 + threadIdx.x) * 8;   // grid 16384 x 256
    float4 a = *reinterpret_cast<const float4*>(X + i);
    float4 b = *reinterpret_cast<const float4*>(X + i + 4);
    f16x8 v;
    v[0]=(f16)a.x; v[1]=(f16)a.y; v[2]=(f16)a.z; v[3]=(f16)a.w;
    v[4]=(f16)b.x; v[5]=(f16)b.y; v[6]=(f16)b.z; v[7]=(f16)b.w;
    *reinterpret_cast<f16x8*>(Xf + i) = v;
}

// ---------- init: Hs[0] from H0 (packed layout) ----------
__global__ void k_init_h(const float* __restrict__ H0, f16* __restrict__ Hs) {
    int tid = blockIdx.x * 256 + threadIdx.x;   // 8192
    int b = tid >> 7, kb = tid & 127;
    float4 x0 = *reinterpret_cast<const float4*>(H0 + (size_t)b*1024 + kb*8);
    float4 x1 = *reinterpret_cast<const float4*>(H0 + (size_t)b*1024 + kb*8 + 4);
    f16x8 v;
    v[0]=(f16)x0.x; v[1]=(f16)x0.y; v[2]=(f16)x0.z; v[3]=(f16)x0.w;
    v[4]=(f16)x1.x; v[5]=(f16)x1.y; v[6]=(f16)x1.z; v[7]=(f16)x1.w;
    size_t idx = (size_t)(b >> 4)*16384 + (size_t)kb*128 + (size_t)(b & 15)*8;
    *reinterpret_cast<f16x8*>(Hs + idx) = v;
}

__global__ void k_zero_flags(unsigned int* __restrict__ flags) {
    flags[blockIdx.x * 256 + threadIdx.x] = 0;   // 2048 u32 (256 logical flags, 32B apart)
}

// ---------- phase 1: input projection GEMM (m97 structure) ----------
// A = Xf f16 [32768][1024] (rows m = b*512+t), B = Wx f16 [2048][1024]
// Both staged via global_load_lds(16B) into linear LDS [128][32] f16.
__global__ __launch_bounds__(256) void k_gemm1(
    const f16* __restrict__ Af, const f16* __restrict__ Bm,
    const float* __restrict__ bh, const float* __restrict__ bo,
    f16* __restrict__ Xh, float* __restrict__ Out)
{
    __shared__ f16 As[128*32];   // 8 KB, linear row-major [128][32]
    __shared__ f16 Bs[128*32];   // 8 KB
    int m0 = blockIdx.x * 128;
    int n0 = blockIdx.y * 128;
    int t = threadIdx.x;
    int l = t & 63, w = t >> 6;
    int wm = w >> 1, wn = w & 1;
    int lm = l & 15, lh = l >> 4;

    f32x4 acc[4][4];
    #pragma unroll
    for (int i = 0; i < 4; i++)
        #pragma unroll
        for (int j = 0; j < 4; j++) acc[i][j] = (f32x4){0.f,0.f,0.f,0.f};

    // per-lane global byte offsets for staging (16 rows x 4 chunks per inst)
    const size_t lgo = (size_t)(l >> 2) * 2048 + (size_t)(l & 3) * 16;

    for (int kt = 0; kt < 32; ++kt) {
        __syncthreads();   // prior frag reads done before overwrite
        {
            const char* ga = (const char*)(Af + (size_t)(m0 + w*32) * 1024 + kt*32);
            const char* gb = (const char*)(Bm + (size_t)(n0 + w*32) * 1024 + kt*32);
            char* la = (char*)As + w * 2048;
            char* lb = (char*)Bs + w * 2048;
            #pragma unroll
            for (int j = 0; j < 2; ++j) {
                __builtin_amdgcn_global_load_lds(
                    (const __attribute__((address_space(1))) void*)(ga + (size_t)j*32768 + lgo),
                    (__attribute__((address_space(3))) void*)(la + j*1024), 16, 0, 0);
                __builtin_amdgcn_global_load_lds(
                    (const __attribute__((address_space(1))) void*)(gb + (size_t)j*32768 + lgo),
                    (__attribute__((address_space(3))) void*)(lb + j*1024), 16, 0, 0);
            }
        }
        asm volatile("s_waitcnt vmcnt(0)" ::: "memory");
        __syncthreads();

        f16x8 af[4], bf[4];
        #pragma unroll
        for (int i = 0; i < 4; i++)
            af[i] = *reinterpret_cast<const f16x8*>(As + (64*wm + 16*i + lm)*32 + 8*lh);
        #pragma unroll
        for (int j = 0; j < 4; j++)
            bf[j] = *reinterpret_cast<const f16x8*>(Bs + (64*wn + 16*j + lm)*32 + 8*lh);
        #pragma unroll
        for (int i = 0; i < 4; i++)
            #pragma unroll
            for (int j = 0; j < 4; j++)
                acc[i][j] = __builtin_amdgcn_mfma_f32_16x16x32_f16(af[i], bf[j], acc[i][j], 0, 0, 0);
    }

    int r0 = lh * 4;
    bool isH = (n0 < 1024);
    #pragma unroll
    for (int i = 0; i < 4; i++)
        #pragma unroll
        for (int j = 0; j < 4; j++) {
            int gmb = m0 + 64*wm + 16*i + r0;
            int gn  = n0 + 64*wn + 16*j + lm;
            #pragma unroll
            for (int r = 0; r < 4; r++) {
                float v = acc[i][j][r];
                int gm = gmb + r;                 // m = b*512 + t
                if (isH) {
                    int tt = gm & 511, bb = gm >> 9;
                    size_t idx = (size_t)tt*65536 + (size_t)(bb>>4)*16384
                               + (size_t)(gn>>3)*128 + (size_t)(bb&15)*8 + (gn&7);
                    Xh[idx] = (f16)(v + bh[gn]);
                } else {
                    Out[(size_t)gm*1024 + (gn - 1024)] = v + bo[gn - 1024];
                }
            }
        }
}

// ---------- matrix squaring: Pout = P*P (B transposed in-LDS) ----------
__global__ __launch_bounds__(256) void k_sq(const f16* __restrict__ P, f16* __restrict__ Pout)
{
    __shared__ f16 As[128][40];
    __shared__ f16 Bs[128][40];
    int m0 = blockIdx.x * 128, n0 = blockIdx.y * 128;
    int t = threadIdx.x;
    int l = t & 63, wid = t >> 6;
    int wm = wid >> 1, wn = wid & 1;
    int lm = l & 15, lh = l >> 4;

    f32x4 acc[4][4];
    #pragma unroll
    for (int i = 0; i < 4; i++)
        #pragma unroll
        for (int j = 0; j < 4; j++) acc[i][j] = (f32x4){0.f,0.f,0.f,0.f};

    for (int kt = 0; kt < 32; ++kt) {
        __syncthreads();
        #pragma unroll
        for (int c = t; c < 512; c += 256) {       // A rows m, k-contig
            int row = c >> 2, q = c & 3;
            *reinterpret_cast<float4*>(&As[row][q*8]) =
                *reinterpret_cast<const float4*>(P + (size_t)(m0+row)*1024 + kt*32 + q*8);
        }
        #pragma unroll
        for (int c = t; c < 512; c += 256) {       // Bs[n][k] = P[k][n0+n]
            int r = c >> 4, q = c & 15;
            f16x8 v = *reinterpret_cast<const f16x8*>(P + (size_t)(kt*32 + r)*1024 + n0 + q*8);
            #pragma unroll
            for (int e = 0; e < 8; ++e) Bs[q*8+e][r] = v[e];
        }
        __syncthreads();

        f16x8 af[4], bf[4];
        #pragma unroll
        for (int i = 0; i < 4; i++)
            af[i] = *reinterpret_cast<const f16x8*>(&As[64*wm + 16*i + lm][8*lh]);
        #pragma unroll
        for (int j = 0; j < 4; j++)
            bf[j] = *reinterpret_cast<const f16x8*>(&Bs[64*wn + 16*j + lm][8*lh]);
        #pragma unroll
        for (int i = 0; i < 4; i++)
            #pragma unroll
            for (int j = 0; j < 4; j++)
                acc[i][j] = __builtin_amdgcn_mfma_f32_16x16x32_f16(af[i], bf[j], acc[i][j], 0, 0, 0);
    }

    int r0 = lh * 4;
    #pragma unroll
    for (int i = 0; i < 4; i++)
        #pragma unroll
        for (int j = 0; j < 4; j++) {
            int gmb = m0 + 64*wm + 16*i + r0;
            int gn  = n0 + 64*wn + 16*j + lm;
            #pragma unroll
            for (int r = 0; r < 4; r++)
                Pout[(size_t)(gmb+r)*1024 + gn] = (f16)acc[i][j][r];
        }
}

// ---------- v-level GEMM: Dst[k] = M * Src[f(2k)] + Src[f(2k+1)] ----------
__global__ __launch_bounds__(256) void k_vlevel(
    const f16* __restrict__ M, const f16* __restrict__ Src, f16* __restrict__ Dst,
    int srcOff, int srcStep, int dstOff, int dstStep)
{
    __shared__ f16 As[128][40];
    __shared__ f16 Bs[128][40];
    int m0 = blockIdx.x * 128;          // rows m = k*64 + b
    int n0 = blockIdx.y * 128;
    int t = threadIdx.x;
    int l = t & 63, wid = t >> 6;
    int wm = wid >> 1, wn = wid & 1;
    int lm = l & 15, lh = l >> 4;

    f32x4 acc[4][4];
    #pragma unroll
    for (int i = 0; i < 4; i++)
        #pragma unroll
        for (int j = 0; j < 4; j++) acc[i][j] = (f32x4){0.f,0.f,0.f,0.f};

    for (int kt = 0; kt < 32; ++kt) {
        __syncthreads();
        #pragma unroll
        for (int c = t; c < 512; c += 256) {   // A from packed src slabs
            int q = c >> 7, r = c & 127;
            int gm = m0 + r;
            int kd = gm >> 6, bb = gm & 63;
            size_t slab = (size_t)(srcOff + srcStep * (2*kd));
            *reinterpret_cast<float4*>(&As[r][q*8]) =
                *reinterpret_cast<const float4*>(Src + slab*65536 + (size_t)(bb>>4)*16384
                                                 + (size_t)(kt*4+q)*128 + (size_t)(bb&15)*8);
        }
        #pragma unroll
        for (int c = t; c < 512; c += 256) {   // B = M row-major
            int row = c >> 2, q = c & 3;
            *reinterpret_cast<float4*>(&Bs[row][q*8]) =
                *reinterpret_cast<const float4*>(M + (size_t)(n0+row)*1024 + kt*32 + q*8);
        }
        __syncthreads();

        f16x8 af[4], bf[4];
        #pragma unroll
        for (int i = 0; i < 4; i++)
            af[i] = *reinterpret_cast<const f16x8*>(&As[64*wm + 16*i + lm][8*lh]);
        #pragma unroll
        for (int j = 0; j < 4; j++)
            bf[j] = *reinterpret_cast<const f16x8*>(&Bs[64*wn + 16*j + lm][8*lh]);
        #pragma unroll
        for (int i = 0; i < 4; i++)
            #pragma unroll
            for (int j = 0; j < 4; j++)
                acc[i][j] = __builtin_amdgcn_mfma_f32_16x16x32_f16(af[i], bf[j], acc[i][j], 0, 0, 0);
    }

    int r0 = lh * 4;
    #pragma unroll
    for (int i = 0; i < 4; i++)
        #pragma unroll
        for (int j = 0; j < 4; j++) {
            int gmb = m0 + 64*wm + 16*i + r0;
            int gn  = n0 + 64*wn + 16*j + lm;
            #pragma unroll
            for (int r = 0; r < 4; r++) {
                int gm = gmb + r;
                int kd = gm >> 6, bb = gm & 63;
                size_t pidx = (size_t)(bb>>4)*16384 + (size_t)(gn>>3)*128
                            + (size_t)(bb&15)*8 + (gn&7);
                size_t aslab = (size_t)(srcOff + srcStep * (2*kd + 1));
                float add = (float)Src[aslab*65536 + pidx];
                size_t dslab = (size_t)(dstOff + dstStep * kd);
                Dst[dslab*65536 + pidx] = (f16)(acc[i][j][r] + add);
            }
        }
}

// ---------- flag-sync recurrence kernel ----------
// mode 1 (CHAIN): 64 WGs. step t: Hs[16t] -> Hs[16t+16], u = Hs[16t+8] (v4).
//   decode: r=wg&7, s=wg>>3: g=bg=r>>1, cg=((r&1)<<3)|s, p=0  (group on XCD pair)
// mode 2 (FILL): 256 WGs. step t: Hs[c*16+t] -> +1, u = Xh[c*16+t], c=p*8+i.
//   decode: r=wg&7, s=wg>>3: g=2r+(s>>4), cg=s&15, p=g>>2, bg=g&3 (group on one XCD)
__global__ void __launch_bounds__(256) __attribute__((amdgpu_waves_per_eu(1, 1)))
k_chain(
    const f16* __restrict__ W,        // [1024][1024] row-major (A or A16)
    const f16* __restrict__ U,        // u base (slab-packed)
    f16* __restrict__ Hs,
    unsigned int* __restrict__ flags,
    int nstep, int mode, int nch)
{
    int wg = blockIdx.x;
    int r_ = wg & 7, s_ = wg >> 3;
    int g, cg, p, bg;
    if (mode == 1) { g = r_ >> 1; cg = ((r_ & 1) << 3) | s_; p = 0;       bg = g;     }
    else           { g = 2*r_ + (s_ >> 4); cg = s_ & 15;     p = g >> 2;  bg = g & 3; }
    int w  = threadIdx.x >> 6;
    int l  = threadIdx.x & 63;
    int lm = l & 15, lh = l >> 4;
    int ccol = cg * 64 + w * 16 + lm;

    __shared__ f16 hbuf[16384];
    __shared__ float lt[4][16][17];

    // register-resident recurrent weights: 16 cols x K=1024 = 128 VGPRs/lane.
    f16x8 bw[32];
    #pragma unroll
    for (int kt = 0; kt < 32; ++kt)
        bw[kt] = *reinterpret_cast<const f16x8*>(W + (size_t)ccol * 1024 + kt*32 + lh*8);
    #pragma unroll
    for (int kt = 0; kt < 32; ++kt)
        asm volatile("" : "+v"(bw[kt]));

    const int flagBase = g * 16;
    int b_ep = l & 15, cb_ep = l >> 4;

    for (int t = 0; t < nstep; ++t) {
        if (t > 0) {
            if (threadIdx.x < 16) {
                unsigned int tgt = (unsigned int)t;
                const unsigned int* fp = &flags[(flagBase + (int)threadIdx.x) * 8];
                while (__hip_atomic_load(fp, __ATOMIC_RELAXED, __HIP_MEMORY_SCOPE_AGENT) < tgt)
                    __builtin_amdgcn_s_sleep(1);
            }
            __syncthreads();
            asm volatile("" ::: "memory");
        }

        for (int i = 0; i < nch; ++i) {
            int c = p * nch + i;
            size_t rSlab, wSlab, uSlab;
            if (mode == 1) { rSlab = (size_t)(16*t); wSlab = rSlab + 16; uSlab = rSlab + 8; }
            else           { rSlab = (size_t)(c*16 + t); wSlab = rSlab + 1; uSlab = rSlab; }

            if (i > 0) __syncthreads();   // hbuf reuse across chunks

            f16x8 xv;
            int cblk = cg*8 + w*2 + cb_ep;
            if (l < 32)
                xv = *reinterpret_cast<const f16x8*>(
                    U + uSlab*65536 + (size_t)bg*16384 + (size_t)cblk*128 + b_ep*8);

            {
                const char* gsrc = (const char*)Hs + (rSlab*65536 + (size_t)bg*16384)*2
                                 + (size_t)w*8192 + (size_t)l*16;
                char* ldst = (char*)hbuf + (size_t)w*8192;
                #pragma unroll
                for (int q = 0; q < 8; ++q)
                    __builtin_amdgcn_global_load_lds(
                        (const __attribute__((address_space(1))) void*)(gsrc + q*1024),
                        (__attribute__((address_space(3))) void*)(ldst + q*1024),
                        16, 0, 0);
            }
            asm volatile("s_waitcnt vmcnt(0)" ::: "memory");
            __syncthreads();

            f32x4 a0 = (f32x4){0.f,0.f,0.f,0.f};
            f32x4 a1 = (f32x4){0.f,0.f,0.f,0.f};
            #pragma unroll
            for (int kt = 0; kt < 32; ++kt) {
                f16x8 af = *reinterpret_cast<const f16x8*>(&hbuf[(size_t)(kt*4 + lh)*128 + lm*8]);
                if (kt & 1) a1 = __builtin_amdgcn_mfma_f32_16x16x32_f16(af, bw[kt], a1, 0, 0, 0);
                else        a0 = __builtin_amdgcn_mfma_f32_16x16x32_f16(af, bw[kt], a0, 0, 0, 0);
            }
            f32x4 acc = a0 + a1;

            #pragma unroll
            for (int r = 0; r < 4; ++r)
                lt[w][lh*4 + r][lm] = acc[r];
            // wave-private RAW through LDS (compiler inserts lgkmcnt)

            if (l < 32) {
                f16x8 hv;
                #pragma unroll
                for (int e = 0; e < 8; ++e)
                    hv[e] = (f16)(lt[w][b_ep][cb_ep*8 + e] + (float)xv[e]);
                f16* dst = Hs + wSlab*65536 + (size_t)bg*16384 + (size_t)cblk*128 + b_ep*8;
                i32x4 iv = __builtin_bit_cast(i32x4, hv);
                asm volatile("global_store_dwordx4 %0, %1, off sc0 sc1"
                             :: "v"(dst), "v"(iv) : "memory");
            }
        }

        asm volatile("s_waitcnt vmcnt(0)" ::: "memory");
        __syncthreads();
        if (threadIdx.x == 0) {
            __builtin_amdgcn_fence(__ATOMIC_RELEASE, "agent");
            __hip_atomic_store(&flags[(flagBase + cg)*8], (unsigned int)(t+1),
                               __ATOMIC_RELAXED, __HIP_MEMORY_SCOPE_AGENT);
        }
    }
}

// ---------- phase 3: output GEMM  Out += Hs @ Wro^T (verified r6) ----------
__global__ __launch_bounds__(256) void k_gemm2(
    const f16* __restrict__ Hs, const f16* __restrict__ Bm, float* __restrict__ Out)
{
    __shared__ f16 As[128][40];
    __shared__ f16 Bs[128][40];
    int m0 = blockIdx.x * 128;          // m' = t*64 + b
    int n0 = blockIdx.y * 128;
    int t = threadIdx.x;
    int l = t & 63, wid = t >> 6;
    int wm = wid >> 1, wn = wid & 1;
    int lm = l & 15, lh = l >> 4;

    f32x4 acc[4][4];
    #pragma unroll
    for (int i = 0; i < 4; i++)
        #pragma unroll
        for (int j = 0; j < 4; j++) acc[i][j] = (f32x4){0.f,0.f,0.f,0.f};

    for (int kt = 0; kt < 32; ++kt) {
        __syncthreads();
        #pragma unroll
        for (int c = t; c < 512; c += 256) {
            int q = c >> 7, r = c & 127;
            int gm = m0 + r;
            int tt = gm >> 6, bb = gm & 63;
            size_t idx = (size_t)tt*65536 + (size_t)(bb>>4)*16384
                       + (size_t)(kt*4 + q)*128 + (size_t)(bb&15)*8;
            *reinterpret_cast<float4*>(&As[r][q*8]) =
                *reinterpret_cast<const float4*>(Hs + idx);
        }
        #pragma unroll
        for (int c = t; c < 512; c += 256) {
            int row = c >> 2, q = c & 3;
            *reinterpret_cast<float4*>(&Bs[row][q*8]) =
                *reinterpret_cast<const float4*>(Bm + (size_t)(n0+row)*1024 + kt*32 + q*8);
        }
        __syncthreads();

        f16x8 af[4], bf[4];
        #pragma unroll
        for (int i = 0; i < 4; i++)
            af[i] = *reinterpret_cast<const f16x8*>(&As[64*wm + 16*i + lm][8*lh]);
        #pragma unroll
        for (int j = 0; j < 4; j++)
            bf[j] = *reinterpret_cast<const f16x8*>(&Bs[64*wn + 16*j + lm][8*lh]);
        #pragma unroll
        for (int i = 0; i < 4; i++)
            #pragma unroll
            for (int j = 0; j < 4; j++)
                acc[i][j] = __builtin_amdgcn_mfma_f32_16x16x32_f16(af[i], bf[j], acc[i][j], 0, 0, 0);
    }

    int r0 = lh * 4;
    #pragma unroll
    for (int i = 0; i < 4; i++)
        #pragma unroll
        for (int j = 0; j < 4; j++) {
            int gmb = m0 + 64*wm + 16*i + r0;
            int gn  = n0 + 64*wn + 16*j + lm;
            #pragma unroll
            for (int r = 0; r < 4; r++) {
                int gm = gmb + r;               // m' = t*64 + b
                int bb = gm & 63, tt = gm >> 6;
                size_t o = ((size_t)bb*512 + tt)*1024 + gn;
                Out[o] += acc[i][j][r];
            }
        }
}

// ---------- workspace layout (bytes) — 136.07 MB total ----------
// [0, 4M)      Wx (gemm1); afterwards Pa @0, Pb @2M (A-power ping-pong)
// [4M, 8M)     Wr  (rows 0..1023 = A = Wrh, rows 1024..2047 = Wro)
// [8M, 72M)    Xh  [512 slabs]
// [72M, 136M)  Hs  [512 slabs]; ALSO Xf f16 [32768][1024] pre-gemm1 (dead after);
//              then V1 -> slabs 1..256, V2 -> odd 257.., V3 -> 2+4m, V4 -> 16c+8
// [136M, +8K)  flags u32[2048] (256 logical flags, 32B stride)

extern "C" void kernel_launch(void* const* d_in, const int* in_sizes, int n_in,
                              void* d_out, int out_size, void* d_ws, size_t ws_size,
                              hipStream_t stream) {
    const float* X  = (const float*)d_in[0];
    const float* H0 = (const float*)d_in[1];
    const float* Wh = (const float*)d_in[2];
    const float* bh = (const float*)d_in[3];
    const float* Wo = (const float*)d_in[4];
    const float* bo = (const float*)d_in[5];
    float* Out = (float*)d_out;

    char* ws = (char*)d_ws;
    f16* Wx = (f16*)(ws);
    f16* Pa = (f16*)(ws);                               // aliases Wx (dead after gemm1)
    f16* Pb = (f16*)(ws + (size_t)2*1024*1024);
    f16* Wr = (f16*)(ws + (size_t)4*1024*1024);
    f16* Xh = (f16*)(ws + (size_t)8*1024*1024);
    f16* Hs = (f16*)(ws + (size_t)8*1024*1024 + (size_t)M_TOT*1024*2);
    f16* Xf = Hs;                                       // aliases Hs (dead until after gemm1)
    unsigned int* flags = (unsigned int*)(ws + (size_t)8*1024*1024 + (size_t)2*M_TOT*1024*2);

    hipLaunchKernelGGL(k_prep_w, dim3(2048), dim3(256), 0, stream, Wh, Wo, Wx, Wr);
    hipLaunchKernelGGL(k_prep_x, dim3(16384), dim3(256), 0, stream, X, Xf);
    hipLaunchKernelGGL(k_gemm1, dim3(256, 16), dim3(256), 0, stream, Xf, Wx, bh, bo, Xh, Out);
    hipLaunchKernelGGL(k_init_h, dim3(32), dim3(256), 0, stream, H0, Hs);   // after gemm1: Xf dead

    // A-power / v-level interleave (each value consumed before overwrite)
    hipLaunchKernelGGL(k_sq, dim3(8,8), dim3(256), 0, stream, Wr, Pa);                   // Pa = A2
    hipLaunchKernelGGL(k_vlevel, dim3(128,8), dim3(256), 0, stream, Wr, Xh, Hs, 0,1, 1,1);     // V1
    hipLaunchKernelGGL(k_vlevel, dim3(64,8),  dim3(256), 0, stream, Pa, Hs, Hs, 1,1, 257,2);   // V2
    hipLaunchKernelGGL(k_sq, dim3(8,8), dim3(256), 0, stream, Pa, Pb);                   // Pb = A4
    hipLaunchKernelGGL(k_vlevel, dim3(32,8),  dim3(256), 0, stream, Pb, Hs, Hs, 257,2, 2,4);   // V3
    hipLaunchKernelGGL(k_sq, dim3(8,8), dim3(256), 0, stream, Pb, Pa);                   // Pa = A8
    hipLaunchKernelGGL(k_vlevel, dim3(16,8),  dim3(256), 0, stream, Pa, Hs, Hs, 2,4, 8,16);    // V4
    hipLaunchKernelGGL(k_sq, dim3(8,8), dim3(256), 0, stream, Pa, Pb);                   // Pb = A16

    // chain: h_{16(t+1)} = A16 h_{16t} + v4_t   (31 steps, 64 WGs)
    hipLaunchKernelGGL(k_zero_flags, dim3(8), dim3(256), 0, stream, flags);
    {
        int nstep = 31, mode = 1, nch = 1;
        void* args[] = { (void*)&Pb, (void*)&Hs, (void*)&Hs, (void*)&flags,
                         (void*)&nstep, (void*)&mode, (void*)&nch };
        if (hipLaunchCooperativeKernel((const void*)k_chain, dim3(64), dim3(256),
                                       args, 0, stream) != hipSuccess) {
            hipLaunchKernelGGL(k_chain, dim3(64), dim3(256), 0, stream,
                               Pb, Hs, Hs, flags, 31, 1, 1);
        }
    }

    // fill: h_{c*16+t+1} = A h_{c*16+t} + u   (15 steps, 32 chunks, 256 WGs x nch=8)
    hipLaunchKernelGGL(k_zero_flags, dim3(8), dim3(256), 0, stream, flags);
    {
        int nstep = 15, mode = 2, nch = 8;
        void* args[] = { (void*)&Wr, (void*)&Xh, (void*)&Hs, (void*)&flags,
                         (void*)&nstep, (void*)&mode, (void*)&nch };
        if (hipLaunchCooperativeKernel((const void*)k_chain, dim3(256), dim3(256),
                                       args, 0, stream) != hipSuccess) {
            hipLaunchKernelGGL(k_chain, dim3(256), dim3(256), 0, stream,
                               Wr, Xh, Hs, flags, 15, 2, 8);
        }
    }

    f16* Wro = Wr + (size_t)1024*1024;
    hipLaunchKernelGGL(k_gemm2, dim3(256, 8), dim3(256), 0, stream, Hs, Wro, Out);
}

// Round 11
// 1106.643 us; speedup vs baseline: 15.2302x; 1.1409x over previous
//
#include <hip/hip_runtime.h>
#include <hip/hip_bf16.h>

// RNNLayer: B=64, T=512, D_IN=D_H=D_OUT=1024.
// h_{t+1} = A h_t + u_t  (A = Wrh, u_t = x_t@Wxh^T + bh);  o_t = x_t@Wxo^T + h_t@Wro^T + bo
// Scan decomposition (sequential depth 511 -> 31 + 15):
//   tree:  v1=A u+u', v2=A2 v1+v1', v3=A4 v2+v2', v4=A8 v3+v3'  (plain GEMMs)
//   chain: h_{16(k+1)} = A16 h_{16k} + v4_k       (31 flag-sync steps, 64 WGs)
//   fill:  h_{16k+tau+1} = A h_{16k+tau} + u      (15 flag-sync steps, 256 WGs, nch=8)
// r10 -> r11: k_vlevel and k_gemm2 staging upgraded to global_load_lds(16B) +
// linear LDS (the lever that took gemm1 525->262 us). A-operand from packed
// slabs maps to LDS [ttloc2][bg4][kblk4][b16][e8]; frag read
// As[wm*2048+i*512+lh*128+lm*8]. B uses gemm1's proven lgo pattern.
// Everything else byte-identical to r10-verified kernels.

typedef _Float16 f16;
typedef _Float16 f16x8 __attribute__((ext_vector_type(8)));
typedef _Float16 f16x4 __attribute__((ext_vector_type(4)));
typedef float f32x4 __attribute__((ext_vector_type(4)));
typedef int i32x4 __attribute__((ext_vector_type(4)));

#define T_LEN 512
#define BATCH 64
#define M_TOT (BATCH * T_LEN)   // 32768

// slab layout (per t): [bg 4][cblk 128][b 16][8] f16 = 65536 elems (128 KB)

// ---------- prep: stacked fp16 weights ----------
__global__ void k_prep_w(const float* __restrict__ Wh, const float* __restrict__ Wo,
                         f16* __restrict__ Wx, f16* __restrict__ Wr) {
    int n = blockIdx.x;              // 0..2047
    int t4 = threadIdx.x * 4;        // 0..1020
    const float* src = (n < 1024) ? (Wh + (size_t)n * 2048)
                                  : (Wo + (size_t)(n - 1024) * 2048);
    float4 a = *reinterpret_cast<const float4*>(src + t4);
    float4 b = *reinterpret_cast<const float4*>(src + 1024 + t4);
    f16x4 va, vb;
    va[0]=(f16)a.x; va[1]=(f16)a.y; va[2]=(f16)a.z; va[3]=(f16)a.w;
    vb[0]=(f16)b.x; vb[1]=(f16)b.y; vb[2]=(f16)b.z; vb[3]=(f16)b.w;
    *reinterpret_cast<f16x4*>(Wx + (size_t)n*1024 + t4) = va;
    *reinterpret_cast<f16x4*>(Wr + (size_t)n*1024 + t4) = vb;
}

// ---------- prep: X f32 -> Xf f16 row-major [32768][1024] ----------
__global__ void k_prep_x(const float* __restrict__ X, f16* __restrict__ Xf) {
    size_t i = ((size_t)blockIdx.x * 256 + threadIdx.x) * 8;   // grid 16384 x 256
    float4 a = *reinterpret_cast<const float4*>(X + i);
    float4 b = *reinterpret_cast<const float4*>(X + i + 4);
    f16x8 v;
    v[0]=(f16)a.x; v[1]=(f16)a.y; v[2]=(f16)a.z; v[3]=(f16)a.w;
    v[4]=(f16)b.x; v[5]=(f16)b.y; v[6]=(f16)b.z; v[7]=(f16)b.w;
    *reinterpret_cast<f16x8*>(Xf + i) = v;
}

// ---------- init: Hs[0] from H0 (packed layout) ----------
__global__ void k_init_h(const float* __restrict__ H0, f16* __restrict__ Hs) {
    int tid = blockIdx.x * 256 + threadIdx.x;   // 8192
    int b = tid >> 7, kb = tid & 127;
    float4 x0 = *reinterpret_cast<const float4*>(H0 + (size_t)b*1024 + kb*8);
    float4 x1 = *reinterpret_cast<const float4*>(H0 + (size_t)b*1024 + kb*8 + 4);
    f16x8 v;
    v[0]=(f16)x0.x; v[1]=(f16)x0.y; v[2]=(f16)x0.z; v[3]=(f16)x0.w;
    v[4]=(f16)x1.x; v[5]=(f16)x1.y; v[6]=(f16)x1.z; v[7]=(f16)x1.w;
    size_t idx = (size_t)(b >> 4)*16384 + (size_t)kb*128 + (size_t)(b & 15)*8;
    *reinterpret_cast<f16x8*>(Hs + idx) = v;
}

__global__ void k_zero_flags(unsigned int* __restrict__ flags) {
    flags[blockIdx.x * 256 + threadIdx.x] = 0;   // 2048 u32 (256 logical flags, 32B apart)
}

// ---------- phase 1: input projection GEMM (m97 structure, verified r10) ----------
__global__ __launch_bounds__(256) void k_gemm1(
    const f16* __restrict__ Af, const f16* __restrict__ Bm,
    const float* __restrict__ bh, const float* __restrict__ bo,
    f16* __restrict__ Xh, float* __restrict__ Out)
{
    __shared__ f16 As[128*32];   // 8 KB, linear row-major [128][32]
    __shared__ f16 Bs[128*32];   // 8 KB
    int m0 = blockIdx.x * 128;
    int n0 = blockIdx.y * 128;
    int t = threadIdx.x;
    int l = t & 63, w = t >> 6;
    int wm = w >> 1, wn = w & 1;
    int lm = l & 15, lh = l >> 4;

    f32x4 acc[4][4];
    #pragma unroll
    for (int i = 0; i < 4; i++)
        #pragma unroll
        for (int j = 0; j < 4; j++) acc[i][j] = (f32x4){0.f,0.f,0.f,0.f};

    const size_t lgo = (size_t)(l >> 2) * 2048 + (size_t)(l & 3) * 16;

    for (int kt = 0; kt < 32; ++kt) {
        __syncthreads();
        {
            const char* ga = (const char*)(Af + (size_t)(m0 + w*32) * 1024 + kt*32);
            const char* gb = (const char*)(Bm + (size_t)(n0 + w*32) * 1024 + kt*32);
            char* la = (char*)As + w * 2048;
            char* lb = (char*)Bs + w * 2048;
            #pragma unroll
            for (int j = 0; j < 2; ++j) {
                __builtin_amdgcn_global_load_lds(
                    (const __attribute__((address_space(1))) void*)(ga + (size_t)j*32768 + lgo),
                    (__attribute__((address_space(3))) void*)(la + j*1024), 16, 0, 0);
                __builtin_amdgcn_global_load_lds(
                    (const __attribute__((address_space(1))) void*)(gb + (size_t)j*32768 + lgo),
                    (__attribute__((address_space(3))) void*)(lb + j*1024), 16, 0, 0);
            }
        }
        asm volatile("s_waitcnt vmcnt(0)" ::: "memory");
        __syncthreads();

        f16x8 af[4], bf[4];
        #pragma unroll
        for (int i = 0; i < 4; i++)
            af[i] = *reinterpret_cast<const f16x8*>(As + (64*wm + 16*i + lm)*32 + 8*lh);
        #pragma unroll
        for (int j = 0; j < 4; j++)
            bf[j] = *reinterpret_cast<const f16x8*>(Bs + (64*wn + 16*j + lm)*32 + 8*lh);
        #pragma unroll
        for (int i = 0; i < 4; i++)
            #pragma unroll
            for (int j = 0; j < 4; j++)
                acc[i][j] = __builtin_amdgcn_mfma_f32_16x16x32_f16(af[i], bf[j], acc[i][j], 0, 0, 0);
    }

    int r0 = lh * 4;
    bool isH = (n0 < 1024);
    #pragma unroll
    for (int i = 0; i < 4; i++)
        #pragma unroll
        for (int j = 0; j < 4; j++) {
            int gmb = m0 + 64*wm + 16*i + r0;
            int gn  = n0 + 64*wn + 16*j + lm;
            #pragma unroll
            for (int r = 0; r < 4; r++) {
                float v = acc[i][j][r];
                int gm = gmb + r;                 // m = b*512 + t
                if (isH) {
                    int tt = gm & 511, bb = gm >> 9;
                    size_t idx = (size_t)tt*65536 + (size_t)(bb>>4)*16384
                               + (size_t)(gn>>3)*128 + (size_t)(bb&15)*8 + (gn&7);
                    Xh[idx] = (f16)(v + bh[gn]);
                } else {
                    Out[(size_t)gm*1024 + (gn - 1024)] = v + bo[gn - 1024];
                }
            }
        }
}

// ---------- matrix squaring: Pout = P*P (B transposed in-LDS; verified r9) ----------
__global__ __launch_bounds__(256) void k_sq(const f16* __restrict__ P, f16* __restrict__ Pout)
{
    __shared__ f16 As[128][40];
    __shared__ f16 Bs[128][40];
    int m0 = blockIdx.x * 128, n0 = blockIdx.y * 128;
    int t = threadIdx.x;
    int l = t & 63, wid = t >> 6;
    int wm = wid >> 1, wn = wid & 1;
    int lm = l & 15, lh = l >> 4;

    f32x4 acc[4][4];
    #pragma unroll
    for (int i = 0; i < 4; i++)
        #pragma unroll
        for (int j = 0; j < 4; j++) acc[i][j] = (f32x4){0.f,0.f,0.f,0.f};

    for (int kt = 0; kt < 32; ++kt) {
        __syncthreads();
        #pragma unroll
        for (int c = t; c < 512; c += 256) {       // A rows m, k-contig
            int row = c >> 2, q = c & 3;
            *reinterpret_cast<float4*>(&As[row][q*8]) =
                *reinterpret_cast<const float4*>(P + (size_t)(m0+row)*1024 + kt*32 + q*8);
        }
        #pragma unroll
        for (int c = t; c < 512; c += 256) {       // Bs[n][k] = P[k][n0+n]
            int r = c >> 4, q = c & 15;
            f16x8 v = *reinterpret_cast<const f16x8*>(P + (size_t)(kt*32 + r)*1024 + n0 + q*8);
            #pragma unroll
            for (int e = 0; e < 8; ++e) Bs[q*8+e][r] = v[e];
        }
        __syncthreads();

        f16x8 af[4], bf[4];
        #pragma unroll
        for (int i = 0; i < 4; i++)
            af[i] = *reinterpret_cast<const f16x8*>(&As[64*wm + 16*i + lm][8*lh]);
        #pragma unroll
        for (int j = 0; j < 4; j++)
            bf[j] = *reinterpret_cast<const f16x8*>(&Bs[64*wn + 16*j + lm][8*lh]);
        #pragma unroll
        for (int i = 0; i < 4; i++)
            #pragma unroll
            for (int j = 0; j < 4; j++)
                acc[i][j] = __builtin_amdgcn_mfma_f32_16x16x32_f16(af[i], bf[j], acc[i][j], 0, 0, 0);
    }

    int r0 = lh * 4;
    #pragma unroll
    for (int i = 0; i < 4; i++)
        #pragma unroll
        for (int j = 0; j < 4; j++) {
            int gmb = m0 + 64*wm + 16*i + r0;
            int gn  = n0 + 64*wn + 16*j + lm;
            #pragma unroll
            for (int r = 0; r < 4; r++)
                Pout[(size_t)(gmb+r)*1024 + gn] = (f16)acc[i][j][r];
        }
}

// ---------- v-level GEMM: Dst[k] = M * Src[f(2k)] + Src[f(2k+1)] ----------
// A from packed slabs via global_load_lds: per K-tile, chunk ch=kdl*4+bg is a
// contiguous 1 KB run at Src + slab(kdl)*65536 + bg*16384 + kt*512 (elems).
// LDS As = [kdl 2][bg 4][kblk 4][b 16][e 8]; frag af[i] = As[wm*2048+i*512+lh*128+lm*8].
__global__ __launch_bounds__(256) void k_vlevel(
    const f16* __restrict__ M, const f16* __restrict__ Src, f16* __restrict__ Dst,
    int srcOff, int srcStep, int dstOff, int dstStep)
{
    __shared__ f16 As[4096];   // 8 KB
    __shared__ f16 Bs[128*32]; // 8 KB, [row][32] linear
    int m0 = blockIdx.x * 128;          // rows m = k*64 + b
    int n0 = blockIdx.y * 128;
    int t = threadIdx.x;
    int l = t & 63, w = t >> 6;
    int wm = w >> 1, wn = w & 1;
    int lm = l & 15, lh = l >> 4;

    f32x4 acc[4][4];
    #pragma unroll
    for (int i = 0; i < 4; i++)
        #pragma unroll
        for (int j = 0; j < 4; j++) acc[i][j] = (f32x4){0.f,0.f,0.f,0.f};

    const size_t lgo = (size_t)(l >> 2) * 2048 + (size_t)(l & 3) * 16;   // B (2048 B/row)
    const int kd0 = m0 >> 6;

    for (int kt = 0; kt < 32; ++kt) {
        __syncthreads();
        {
            // A: 8 chunks of 1 KB; wave w stages chunks 2w, 2w+1
            #pragma unroll
            for (int j = 0; j < 2; ++j) {
                int ch  = w*2 + j;               // 0..7
                int kdl = ch >> 2, bgc = ch & 3;
                size_t slab = (size_t)(srcOff + srcStep * (2*(kd0 + kdl)));
                const char* gsrc = (const char*)(Src + slab*65536
                                    + (size_t)bgc*16384 + (size_t)kt*512) + (size_t)l*16;
                __builtin_amdgcn_global_load_lds(
                    (const __attribute__((address_space(1))) void*)gsrc,
                    (__attribute__((address_space(3))) void*)((char*)As + ch*1024), 16, 0, 0);
            }
            // B: rows n0 + w*32 .. +32 (gemm1 pattern)
            const char* gb = (const char*)(M + (size_t)(n0 + w*32) * 1024 + kt*32);
            char* lb = (char*)Bs + w * 2048;
            #pragma unroll
            for (int j = 0; j < 2; ++j)
                __builtin_amdgcn_global_load_lds(
                    (const __attribute__((address_space(1))) void*)(gb + (size_t)j*32768 + lgo),
                    (__attribute__((address_space(3))) void*)(lb + j*1024), 16, 0, 0);
        }
        asm volatile("s_waitcnt vmcnt(0)" ::: "memory");
        __syncthreads();

        f16x8 af[4], bf[4];
        #pragma unroll
        for (int i = 0; i < 4; i++)
            af[i] = *reinterpret_cast<const f16x8*>(As + wm*2048 + i*512 + lh*128 + lm*8);
        #pragma unroll
        for (int j = 0; j < 4; j++)
            bf[j] = *reinterpret_cast<const f16x8*>(Bs + (64*wn + 16*j + lm)*32 + 8*lh);
        #pragma unroll
        for (int i = 0; i < 4; i++)
            #pragma unroll
            for (int j = 0; j < 4; j++)
                acc[i][j] = __builtin_amdgcn_mfma_f32_16x16x32_f16(af[i], bf[j], acc[i][j], 0, 0, 0);
    }

    int r0 = lh * 4;
    #pragma unroll
    for (int i = 0; i < 4; i++)
        #pragma unroll
        for (int j = 0; j < 4; j++) {
            int gmb = m0 + 64*wm + 16*i + r0;
            int gn  = n0 + 64*wn + 16*j + lm;
            #pragma unroll
            for (int r = 0; r < 4; r++) {
                int gm = gmb + r;
                int kd = gm >> 6, bb = gm & 63;
                size_t pidx = (size_t)(bb>>4)*16384 + (size_t)(gn>>3)*128
                            + (size_t)(bb&15)*8 + (gn&7);
                size_t aslab = (size_t)(srcOff + srcStep * (2*kd + 1));
                float add = (float)Src[aslab*65536 + pidx];
                size_t dslab = (size_t)(dstOff + dstStep * kd);
                Dst[dslab*65536 + pidx] = (f16)(acc[i][j][r] + add);
            }
        }
}

// ---------- flag-sync recurrence kernel (verified r9/r10) ----------
// mode 1 (CHAIN): 64 WGs. step t: Hs[16t] -> Hs[16t+16], u = Hs[16t+8] (v4).
//   decode: r=wg&7, s=wg>>3: g=bg=r>>1, cg=((r&1)<<3)|s, p=0  (group on XCD pair)
// mode 2 (FILL): 256 WGs. step t: Hs[c*16+t] -> +1, u = Xh[c*16+t], c=p*8+i.
//   decode: r=wg&7, s=wg>>3: g=2r+(s>>4), cg=s&15, p=g>>2, bg=g&3 (group on one XCD)
__global__ void __launch_bounds__(256) __attribute__((amdgpu_waves_per_eu(1, 1)))
k_chain(
    const f16* __restrict__ W,        // [1024][1024] row-major (A or A16)
    const f16* __restrict__ U,        // u base (slab-packed)
    f16* __restrict__ Hs,
    unsigned int* __restrict__ flags,
    int nstep, int mode, int nch)
{
    int wg = blockIdx.x;
    int r_ = wg & 7, s_ = wg >> 3;
    int g, cg, p, bg;
    if (mode == 1) { g = r_ >> 1; cg = ((r_ & 1) << 3) | s_; p = 0;       bg = g;     }
    else           { g = 2*r_ + (s_ >> 4); cg = s_ & 15;     p = g >> 2;  bg = g & 3; }
    int w  = threadIdx.x >> 6;
    int l  = threadIdx.x & 63;
    int lm = l & 15, lh = l >> 4;
    int ccol = cg * 64 + w * 16 + lm;

    __shared__ f16 hbuf[16384];
    __shared__ float lt[4][16][17];

    f16x8 bw[32];
    #pragma unroll
    for (int kt = 0; kt < 32; ++kt)
        bw[kt] = *reinterpret_cast<const f16x8*>(W + (size_t)ccol * 1024 + kt*32 + lh*8);
    #pragma unroll
    for (int kt = 0; kt < 32; ++kt)
        asm volatile("" : "+v"(bw[kt]));

    const int flagBase = g * 16;
    int b_ep = l & 15, cb_ep = l >> 4;

    for (int t = 0; t < nstep; ++t) {
        if (t > 0) {
            if (threadIdx.x < 16) {
                unsigned int tgt = (unsigned int)t;
                const unsigned int* fp = &flags[(flagBase + (int)threadIdx.x) * 8];
                while (__hip_atomic_load(fp, __ATOMIC_RELAXED, __HIP_MEMORY_SCOPE_AGENT) < tgt)
                    __builtin_amdgcn_s_sleep(1);
            }
            __syncthreads();
            asm volatile("" ::: "memory");
        }

        for (int i = 0; i < nch; ++i) {
            int c = p * nch + i;
            size_t rSlab, wSlab, uSlab;
            if (mode == 1) { rSlab = (size_t)(16*t); wSlab = rSlab + 16; uSlab = rSlab + 8; }
            else           { rSlab = (size_t)(c*16 + t); wSlab = rSlab + 1; uSlab = rSlab; }

            if (i > 0) __syncthreads();   // hbuf reuse across chunks

            f16x8 xv;
            int cblk = cg*8 + w*2 + cb_ep;
            if (l < 32)
                xv = *reinterpret_cast<const f16x8*>(
                    U + uSlab*65536 + (size_t)bg*16384 + (size_t)cblk*128 + b_ep*8);

            {
                const char* gsrc = (const char*)Hs + (rSlab*65536 + (size_t)bg*16384)*2
                                 + (size_t)w*8192 + (size_t)l*16;
                char* ldst = (char*)hbuf + (size_t)w*8192;
                #pragma unroll
                for (int q = 0; q < 8; ++q)
                    __builtin_amdgcn_global_load_lds(
                        (const __attribute__((address_space(1))) void*)(gsrc + q*1024),
                        (__attribute__((address_space(3))) void*)(ldst + q*1024),
                        16, 0, 0);
            }
            asm volatile("s_waitcnt vmcnt(0)" ::: "memory");
            __syncthreads();

            f32x4 a0 = (f32x4){0.f,0.f,0.f,0.f};
            f32x4 a1 = (f32x4){0.f,0.f,0.f,0.f};
            #pragma unroll
            for (int kt = 0; kt < 32; ++kt) {
                f16x8 af = *reinterpret_cast<const f16x8*>(&hbuf[(size_t)(kt*4 + lh)*128 + lm*8]);
                if (kt & 1) a1 = __builtin_amdgcn_mfma_f32_16x16x32_f16(af, bw[kt], a1, 0, 0, 0);
                else        a0 = __builtin_amdgcn_mfma_f32_16x16x32_f16(af, bw[kt], a0, 0, 0, 0);
            }
            f32x4 acc = a0 + a1;

            #pragma unroll
            for (int r = 0; r < 4; ++r)
                lt[w][lh*4 + r][lm] = acc[r];
            // wave-private RAW through LDS (compiler inserts lgkmcnt)

            if (l < 32) {
                f16x8 hv;
                #pragma unroll
                for (int e = 0; e < 8; ++e)
                    hv[e] = (f16)(lt[w][b_ep][cb_ep*8 + e] + (float)xv[e]);
                f16* dst = Hs + wSlab*65536 + (size_t)bg*16384 + (size_t)cblk*128 + b_ep*8;
                i32x4 iv = __builtin_bit_cast(i32x4, hv);
                asm volatile("global_store_dwordx4 %0, %1, off sc0 sc1"
                             :: "v"(dst), "v"(iv) : "memory");
            }
        }

        asm volatile("s_waitcnt vmcnt(0)" ::: "memory");
        __syncthreads();
        if (threadIdx.x == 0) {
            __builtin_amdgcn_fence(__ATOMIC_RELEASE, "agent");
            __hip_atomic_store(&flags[(flagBase + cg)*8], (unsigned int)(t+1),
                               __ATOMIC_RELAXED, __HIP_MEMORY_SCOPE_AGENT);
        }
    }
}

// ---------- phase 3: output GEMM  Out += Hs @ Wro^T ----------
// A staging identical to k_vlevel (slab = tt, srcStep-free); B = Wro rows.
__global__ __launch_bounds__(256) void k_gemm2(
    const f16* __restrict__ Hs, const f16* __restrict__ Bm, float* __restrict__ Out)
{
    __shared__ f16 As[4096];   // 8 KB: [ttloc2][bg4][kblk4][b16][e8]
    __shared__ f16 Bs[128*32]; // 8 KB
    int m0 = blockIdx.x * 128;          // m' = t*64 + b
    int n0 = blockIdx.y * 128;
    int t = threadIdx.x;
    int l = t & 63, w = t >> 6;
    int wm = w >> 1, wn = w & 1;
    int lm = l & 15, lh = l >> 4;

    f32x4 acc[4][4];
    #pragma unroll
    for (int i = 0; i < 4; i++)
        #pragma unroll
        for (int j = 0; j < 4; j++) acc[i][j] = (f32x4){0.f,0.f,0.f,0.f};

    const size_t lgo = (size_t)(l >> 2) * 2048 + (size_t)(l & 3) * 16;
    const int tt0 = m0 >> 6;

    for (int kt = 0; kt < 32; ++kt) {
        __syncthreads();
        {
            #pragma unroll
            for (int j = 0; j < 2; ++j) {
                int ch  = w*2 + j;               // 0..7
                int ttl = ch >> 2, bgc = ch & 3;
                const char* gsrc = (const char*)(Hs + (size_t)(tt0 + ttl)*65536
                                    + (size_t)bgc*16384 + (size_t)kt*512) + (size_t)l*16;
                __builtin_amdgcn_global_load_lds(
                    (const __attribute__((address_space(1))) void*)gsrc,
                    (__attribute__((address_space(3))) void*)((char*)As + ch*1024), 16, 0, 0);
            }
            const char* gb = (const char*)(Bm + (size_t)(n0 + w*32) * 1024 + kt*32);
            char* lb = (char*)Bs + w * 2048;
            #pragma unroll
            for (int j = 0; j < 2; ++j)
                __builtin_amdgcn_global_load_lds(
                    (const __attribute__((address_space(1))) void*)(gb + (size_t)j*32768 + lgo),
                    (__attribute__((address_space(3))) void*)(lb + j*1024), 16, 0, 0);
        }
        asm volatile("s_waitcnt vmcnt(0)" ::: "memory");
        __syncthreads();

        f16x8 af[4], bf[4];
        #pragma unroll
        for (int i = 0; i < 4; i++)
            af[i] = *reinterpret_cast<const f16x8*>(As + wm*2048 + i*512 + lh*128 + lm*8);
        #pragma unroll
        for (int j = 0; j < 4; j++)
            bf[j] = *reinterpret_cast<const f16x8*>(Bs + (64*wn + 16*j + lm)*32 + 8*lh);
        #pragma unroll
        for (int i = 0; i < 4; i++)
            #pragma unroll
            for (int j = 0; j < 4; j++)
                acc[i][j] = __builtin_amdgcn_mfma_f32_16x16x32_f16(af[i], bf[j], acc[i][j], 0, 0, 0);
    }

    int r0 = lh * 4;
    #pragma unroll
    for (int i = 0; i < 4; i++)
        #pragma unroll
        for (int j = 0; j < 4; j++) {
            int gmb = m0 + 64*wm + 16*i + r0;
            int gn  = n0 + 64*wn + 16*j + lm;
            #pragma unroll
            for (int r = 0; r < 4; r++) {
                int gm = gmb + r;               // m' = t*64 + b
                int bb = gm & 63, tt = gm >> 6;
                size_t o = ((size_t)bb*512 + tt)*1024 + gn;
                Out[o] += acc[i][j][r];
            }
        }
}

// ---------- workspace layout (bytes) — 136.07 MB total ----------
// [0, 4M)      Wx (gemm1); afterwards Pa @0, Pb @2M (A-power ping-pong)
// [4M, 8M)     Wr  (rows 0..1023 = A = Wrh, rows 1024..2047 = Wro)
// [8M, 72M)    Xh  [512 slabs]
// [72M, 136M)  Hs  [512 slabs]; ALSO Xf f16 [32768][1024] pre-gemm1 (dead after);
//              then V1 -> slabs 1..256, V2 -> odd 257.., V3 -> 2+4m, V4 -> 16c+8
// [136M, +8K)  flags u32[2048] (256 logical flags, 32B stride)

extern "C" void kernel_launch(void* const* d_in, const int* in_sizes, int n_in,
                              void* d_out, int out_size, void* d_ws, size_t ws_size,
                              hipStream_t stream) {
    const float* X  = (const float*)d_in[0];
    const float* H0 = (const float*)d_in[1];
    const float* Wh = (const float*)d_in[2];
    const float* bh = (const float*)d_in[3];
    const float* Wo = (const float*)d_in[4];
    const float* bo = (const float*)d_in[5];
    float* Out = (float*)d_out;

    char* ws = (char*)d_ws;
    f16* Wx = (f16*)(ws);
    f16* Pa = (f16*)(ws);                               // aliases Wx (dead after gemm1)
    f16* Pb = (f16*)(ws + (size_t)2*1024*1024);
    f16* Wr = (f16*)(ws + (size_t)4*1024*1024);
    f16* Xh = (f16*)(ws + (size_t)8*1024*1024);
    f16* Hs = (f16*)(ws + (size_t)8*1024*1024 + (size_t)M_TOT*1024*2);
    f16* Xf = Hs;                                       // aliases Hs (dead until after gemm1)
    unsigned int* flags = (unsigned int*)(ws + (size_t)8*1024*1024 + (size_t)2*M_TOT*1024*2);

    hipLaunchKernelGGL(k_prep_w, dim3(2048), dim3(256), 0, stream, Wh, Wo, Wx, Wr);
    hipLaunchKernelGGL(k_prep_x, dim3(16384), dim3(256), 0, stream, X, Xf);
    hipLaunchKernelGGL(k_gemm1, dim3(256, 16), dim3(256), 0, stream, Xf, Wx, bh, bo, Xh, Out);
    hipLaunchKernelGGL(k_init_h, dim3(32), dim3(256), 0, stream, H0, Hs);   // after gemm1: Xf dead

    // A-power / v-level interleave (each value consumed before overwrite)
    hipLaunchKernelGGL(k_sq, dim3(8,8), dim3(256), 0, stream, Wr, Pa);                   // Pa = A2
    hipLaunchKernelGGL(k_vlevel, dim3(128,8), dim3(256), 0, stream, Wr, Xh, Hs, 0,1, 1,1);     // V1
    hipLaunchKernelGGL(k_vlevel, dim3(64,8),  dim3(256), 0, stream, Pa, Hs, Hs, 1,1, 257,2);   // V2
    hipLaunchKernelGGL(k_sq, dim3(8,8), dim3(256), 0, stream, Pa, Pb);                   // Pb = A4
    hipLaunchKernelGGL(k_vlevel, dim3(32,8),  dim3(256), 0, stream, Pb, Hs, Hs, 257,2, 2,4);   // V3
    hipLaunchKernelGGL(k_sq, dim3(8,8), dim3(256), 0, stream, Pb, Pa);                   // Pa = A8
    hipLaunchKernelGGL(k_vlevel, dim3(16,8),  dim3(256), 0, stream, Pa, Hs, Hs, 2,4, 8,16);    // V4
    hipLaunchKernelGGL(k_sq, dim3(8,8), dim3(256), 0, stream, Pa, Pb);                   // Pb = A16

    // chain: h_{16(t+1)} = A16 h_{16t} + v4_t   (31 steps, 64 WGs)
    hipLaunchKernelGGL(k_zero_flags, dim3(8), dim3(256), 0, stream, flags);
    {
        int nstep = 31, mode = 1, nch = 1;
        void* args[] = { (void*)&Pb, (void*)&Hs, (void*)&Hs, (void*)&flags,
                         (void*)&nstep, (void*)&mode, (void*)&nch };
        if (hipLaunchCooperativeKernel((const void*)k_chain, dim3(64), dim3(256),
                                       args, 0, stream) != hipSuccess) {
            hipLaunchKernelGGL(k_chain, dim3(64), dim3(256), 0, stream,
                               Pb, Hs, Hs, flags, 31, 1, 1);
        }
    }

    // fill: h_{c*16+t+1} = A h_{c*16+t} + u   (15 steps, 32 chunks, 256 WGs x nch=8)
    hipLaunchKernelGGL(k_zero_flags, dim3(8), dim3(256), 0, stream, flags);
    {
        int nstep = 15, mode = 2, nch = 8;
        void* args[] = { (void*)&Wr, (void*)&Xh, (void*)&Hs, (void*)&flags,
                         (void*)&nstep, (void*)&mode, (void*)&nch };
        if (hipLaunchCooperativeKernel((const void*)k_chain, dim3(256), dim3(256),
                                       args, 0, stream) != hipSuccess) {
            hipLaunchKernelGGL(k_chain, dim3(256), dim3(256), 0, stream,
                               Wr, Xh, Hs, flags, 15, 2, 8);
        }
    }

    f16* Wro = Wr + (size_t)1024*1024;
    hipLaunchKernelGGL(k_gemm2, dim3(256, 8), dim3(256), 0, stream, Hs, Wro, Out);
}